// Round 10
// baseline (525.922 us; speedup 1.0000x reference)
//
#include <hip/hip_runtime.h>
#include <cstddef>

// MVMGIN round 10:
//  - k_gin: BM 128 -> 64 (grid 625 -> 1250 blocks, Tsh 16KB). Round-9 counters
//    showed k_gin grid-starved (2.4 blocks/CU, Occ 20%); this doubles resident
//    blocks without touching the arithmetic.
// Carried: k_giru B-in-LDS/A-direct; k_gin weights direct (L1-resident); separate
// k_pool; global scores folded into qkg GEMM; classifier K=512 fusion; 2-edge/wave
// k_lg; CSR gather; bf16 everywhere; q_l/Wl2/blv foldings; bk_* dropped.
// Outputs (f32, concat): logits(E,5) | ew(E,8) | h_before(N,8,128) | a_g(E,8)

#define HSZ 128
typedef unsigned short ushortT;
typedef unsigned int uintT;
typedef short short8 __attribute__((ext_vector_type(8)));
typedef float f32x4 __attribute__((ext_vector_type(4)));

__device__ __forceinline__ float sigm(float x) { return 1.f / (1.f + __expf(-x)); }

__device__ __forceinline__ ushortT f2bf(float f) {
  unsigned int u = __float_as_uint(f);
  u += 0x7fffu + ((u >> 16) & 1u);
  return (ushortT)(u >> 16);
}
__device__ __forceinline__ float bf2f(ushortT u) {
  return __uint_as_float(((unsigned int)u) << 16);
}
__device__ __forceinline__ float bflo(uintT u) { return __uint_as_float(u << 16); }
__device__ __forceinline__ float bfhi(uintT u) { return __uint_as_float(u & 0xffff0000u); }
__device__ __forceinline__ uintT pk2bf(float a, float b) {
  return ((uintT)f2bf(b) << 16) | (uintT)f2bf(a);
}

// XOR-swizzled LDS chunk index (in shorts): row stride 64 shorts.
__device__ __forceinline__ int swzA(int row, int chunk) {
  return row * 64 + (((chunk ^ row) & 7) << 3);
}
__device__ __forceinline__ int swzT(int row, int chunk) {
  return row * 128 + (((chunk & 8) | ((chunk ^ row) & 7)) << 3);
}

// ---------------- bf16 MFMA GEMM (generic, LDS-staged) ----------------
// ASRC: 0=A1; 4=concat{A1(128), A2(256), A3(128)} bf16. ABF: A bf16 (K%64==0).
template<int ASRC, int ACT, bool OUTBF, bool ABF, bool WBF>
__global__ __launch_bounds__(256) void gemm_bf(
    const void* __restrict__ A1, const void* __restrict__ A2, const void* __restrict__ A3,
    const void* __restrict__ W, const float* __restrict__ bias,
    void* __restrict__ out_, int M, int K, int Nout)
{
  __shared__ short Ash[128 * 64];
  __shared__ short Bsh[128 * 64];
  float* out = (float*)out_;
  ushortT* outh = (ushortT*)out_;
  const int tid = threadIdx.x;
  const int m0 = blockIdx.x * 128;
  const int n0 = blockIdx.y * 128;
  const int l = tid & 63, w = tid >> 6;
  const int wr = w >> 1, wc = w & 1;
  const int lr = l & 15, lq = l >> 4;
  f32x4 acc[4][4] = {};

  for (int k0 = 0; k0 < K; k0 += 64) {
    __syncthreads();
    const bool fast = (k0 + 64 <= K);
    #pragma unroll
    for (int i = 0; i < 4; ++i) {
      int c = i * 256 + tid;
      int row = c >> 3, seg = c & 7;
      int kb = k0 + seg * 8;
      // ---- stage A ----
      {
        int m = m0 + row;
        short8 pk;
        if (ABF) {
          if (m < M) {
            if (ASRC == 4) {
              if (kb < 128)
                pk = *reinterpret_cast<const short8*>((const ushortT*)A1 + (size_t)m * 128 + kb);
              else if (kb < 384)
                pk = *reinterpret_cast<const short8*>((const ushortT*)A2 + (size_t)m * 256 + (kb - 128));
              else
                pk = *reinterpret_cast<const short8*>((const ushortT*)A3 + (size_t)m * 128 + (kb - 384));
            } else {
              pk = *reinterpret_cast<const short8*>((const ushortT*)A1 + (size_t)m * K + kb);
            }
          } else {
            #pragma unroll
            for (int j = 0; j < 8; ++j) pk[j] = 0;
          }
        } else {
          const float* A1f = (const float*)A1;
          float v[8];
          if (fast && m < M) {
            const float4* p = reinterpret_cast<const float4*>(A1f + (size_t)m * K + kb);
            float4 x0 = p[0], x1 = p[1];
            v[0]=x0.x; v[1]=x0.y; v[2]=x0.z; v[3]=x0.w;
            v[4]=x1.x; v[5]=x1.y; v[6]=x1.z; v[7]=x1.w;
          } else {
            #pragma unroll
            for (int j = 0; j < 8; ++j) {
              int k = kb + j;
              v[j] = (m < M && k < K) ? A1f[(size_t)m * K + k] : 0.f;
            }
          }
          #pragma unroll
          for (int j = 0; j < 8; ++j) pk[j] = (short)f2bf(v[j]);
        }
        *reinterpret_cast<short8*>(&Ash[swzA(row, seg)]) = pk;
      }
      // ---- stage B ----
      {
        int nn = n0 + row;
        short8 pk;
        if (WBF) {
          if (nn < Nout)
            pk = *reinterpret_cast<const short8*>((const ushortT*)W + (size_t)nn * K + kb);
          else {
            #pragma unroll
            for (int j = 0; j < 8; ++j) pk[j] = 0;
          }
        } else {
          const float* Wf = (const float*)W;
          float v[8];
          if (fast && nn < Nout) {
            const float4* p = reinterpret_cast<const float4*>(Wf + (size_t)nn * K + kb);
            float4 x0 = p[0], x1 = p[1];
            v[0]=x0.x; v[1]=x0.y; v[2]=x0.z; v[3]=x0.w;
            v[4]=x1.x; v[5]=x1.y; v[6]=x1.z; v[7]=x1.w;
          } else {
            #pragma unroll
            for (int j = 0; j < 8; ++j) {
              int k = kb + j;
              v[j] = (nn < Nout && k < K) ? Wf[(size_t)nn * K + k] : 0.f;
            }
          }
          #pragma unroll
          for (int j = 0; j < 8; ++j) pk[j] = (short)f2bf(v[j]);
        }
        *reinterpret_cast<short8*>(&Bsh[swzA(row, seg)]) = pk;
      }
    }
    __syncthreads();
    #pragma unroll
    for (int ks = 0; ks < 2; ++ks) {
      short8 a[4], b[4];
      #pragma unroll
      for (int mi = 0; mi < 4; ++mi)
        a[mi] = *reinterpret_cast<const short8*>(&Ash[swzA(wr*64 + mi*16 + lr, ks*4 + lq)]);
      #pragma unroll
      for (int ni = 0; ni < 4; ++ni)
        b[ni] = *reinterpret_cast<const short8*>(&Bsh[swzA(wc*64 + ni*16 + lr, ks*4 + lq)]);
      #pragma unroll
      for (int mi = 0; mi < 4; ++mi)
        #pragma unroll
        for (int ni = 0; ni < 4; ++ni)
          acc[mi][ni] = __builtin_amdgcn_mfma_f32_16x16x32_bf16(a[mi], b[ni], acc[mi][ni], 0, 0, 0);
    }
  }
  #pragma unroll
  for (int ni = 0; ni < 4; ++ni) {
    int col = n0 + wc*64 + ni*16 + lr;
    if (col >= Nout) continue;
    float bz = bias ? bias[col] : 0.f;
    #pragma unroll
    for (int mi = 0; mi < 4; ++mi) {
      int mb = m0 + wr*64 + mi*16 + lq*4;
      #pragma unroll
      for (int r = 0; r < 4; ++r) {
        int m = mb + r;
        if (m >= M) continue;
        float vv = acc[mi][ni][r] + bz;
        if (ACT == 1) vv = fmaxf(vv, 0.f);
        size_t o = (size_t)m * Nout + col;
        if (OUTBF) outh[o] = f2bf(vv); else out[o] = vv;
      }
    }
  }
}

// ---------------- fused GIN layer (BM=64, Tsh 16KB, weights direct) ----------
// 2x2 waves: wave (wr,wc) owns rows wr*32+mi*16 (mi<2), cols wc*64+ni*16 (ni<4).
// LMODE 1: A = hb(bcast over v) + aggb; base = bf2f(hb bcast); out -> houtb bf16
// LMODE 2: A = hb + aggb;               base = bf2f(hb);       out -> houtf f32
template<int LMODE>
__global__ __launch_bounds__(256) void k_gin(
    const ushortT* __restrict__ hb, const ushortT* __restrict__ aggb,
    float* __restrict__ houtf, ushortT* __restrict__ houtb,
    const ushortT* __restrict__ W1b, const float* __restrict__ b1,
    const ushortT* __restrict__ W2b, const float* __restrict__ b2, int M)
{
  __shared__ short Tsh[8192];    // 64 x 128 bf16 (swzT), 16 KB
  const int tid = threadIdx.x;
  const int m0 = blockIdx.x * 64;
  const int l = tid & 63, w = tid >> 6;
  const int wr = w >> 1, wc = w & 1;
  const int lr = l & 15, lq = l >> 4;
  f32x4 acc[2][4] = {};

  // ---- phase 1: t = (h+agg) @ W1^T  (A and B direct from global) ----
  #pragma unroll
  for (int kk = 0; kk < 4; ++kk) {
    const int kof = kk * 32 + lq * 8;
    short8 a[2], b[4];
    #pragma unroll
    for (int mi = 0; mi < 2; ++mi) {
      int m = m0 + wr*32 + mi*16 + lr;
      if (m < M) {
        short8 hv;
        if (LMODE == 1) hv = *reinterpret_cast<const short8*>(hb + ((size_t)(m >> 3)) * 128 + kof);
        else            hv = *reinterpret_cast<const short8*>(hb + (size_t)m * 128 + kof);
        short8 av = *reinterpret_cast<const short8*>(aggb + (size_t)m * 128 + kof);
        #pragma unroll
        for (int j = 0; j < 8; ++j)
          a[mi][j] = (short)f2bf(bf2f((ushortT)hv[j]) + bf2f((ushortT)av[j]));
      } else {
        #pragma unroll
        for (int j = 0; j < 8; ++j) a[mi][j] = 0;
      }
    }
    #pragma unroll
    for (int ni = 0; ni < 4; ++ni)
      b[ni] = *reinterpret_cast<const short8*>(W1b + (size_t)(wc*64 + ni*16 + lr) * 128 + kof);
    #pragma unroll
    for (int mi = 0; mi < 2; ++mi)
      #pragma unroll
      for (int ni = 0; ni < 4; ++ni)
        acc[mi][ni] = __builtin_amdgcn_mfma_f32_16x16x32_bf16(a[mi], b[ni], acc[mi][ni], 0, 0, 0);
  }
  // ---- t = relu(acc + b1) -> Tsh ----
  {
    float b1v[4];
    #pragma unroll
    for (int ni = 0; ni < 4; ++ni) b1v[ni] = b1[wc*64 + ni*16 + lr];
    #pragma unroll
    for (int mi = 0; mi < 2; ++mi)
      #pragma unroll
      for (int ni = 0; ni < 4; ++ni) {
        int col = wc*64 + ni*16 + lr;
        #pragma unroll
        for (int r = 0; r < 4; ++r) {
          int row = wr*32 + mi*16 + lq*4 + r;
          float v = fmaxf(acc[mi][ni][r] + b1v[ni], 0.f);
          Tsh[swzT(row, col >> 3) + (col & 7)] = (short)f2bf(v);
        }
      }
  }
  __syncthreads();
  // ---- phase 2: upd = t @ W2^T (B direct from global) ----
  f32x4 acc2[2][4] = {};
  #pragma unroll
  for (int kk = 0; kk < 4; ++kk) {
    const int kof = kk * 32 + lq * 8;
    short8 a[2], b[4];
    #pragma unroll
    for (int mi = 0; mi < 2; ++mi)
      a[mi] = *reinterpret_cast<const short8*>(&Tsh[swzT(wr*32 + mi*16 + lr, kk*4 + lq)]);
    #pragma unroll
    for (int ni = 0; ni < 4; ++ni)
      b[ni] = *reinterpret_cast<const short8*>(W2b + (size_t)(wc*64 + ni*16 + lr) * 128 + kof);
    #pragma unroll
    for (int mi = 0; mi < 2; ++mi)
      #pragma unroll
      for (int ni = 0; ni < 4; ++ni)
        acc2[mi][ni] = __builtin_amdgcn_mfma_f32_16x16x32_bf16(a[mi], b[ni], acc2[mi][ni], 0, 0, 0);
  }
  // ---- epilogue: out = base + upd + b2 ----
  {
    float b2v[4];
    #pragma unroll
    for (int ni = 0; ni < 4; ++ni) b2v[ni] = b2[wc*64 + ni*16 + lr];
    #pragma unroll
    for (int ni = 0; ni < 4; ++ni) {
      int col = wc*64 + ni*16 + lr;
      #pragma unroll
      for (int mi = 0; mi < 2; ++mi) {
        int mb = m0 + wr*32 + mi*16 + lq*4;
        #pragma unroll
        for (int r = 0; r < 4; ++r) {
          int m = mb + r;
          if (m >= M) continue;
          float base = (LMODE == 1) ? bf2f(hb[((size_t)(m >> 3)) * 128 + col])
                                    : bf2f(hb[(size_t)m * 128 + col]);
          float ho = base + acc2[mi][ni][r] + b2v[ni];
          if (LMODE == 1) houtb[(size_t)m * 128 + col] = f2bf(ho);
          else            houtf[(size_t)m * 128 + col] = ho;
        }
      }
    }
  }
}

// ---------------- fused gi GEMM + GRU (B staged in LDS, A direct) -------
__global__ __launch_bounds__(512) void k_giru(
    const float* __restrict__ hf, const float* __restrict__ te,
    const ushortT* __restrict__ Wihb, const float* __restrict__ b_ih,
    const ushortT* __restrict__ ghb, const ushortT* __restrict__ memb,
    ushortT* __restrict__ hnb, int M)
{
  __shared__ short Bsh[24576];    // 384 x 64 bf16 (swzA), 48 KB -> 3 blocks/CU
  const int tid = threadIdx.x;
  const int m0 = blockIdx.x * 64;
  const int l = tid & 63, w = tid >> 6;
  const int lr = l & 15, lq = l >> 4;
  const int r0 = (w >> 1) * 16, c0 = (w & 1) * 64;
  f32x4 acc[3][4] = {};

  for (int ks2 = 0; ks2 < 2; ++ks2) {
    if (ks2) __syncthreads();
    #pragma unroll
    for (int i = 0; i < 6; ++i) {           // 3072 chunks / 512 threads
      int c = i * 512 + tid;
      int row = c >> 3, seg = c & 7;
      *reinterpret_cast<short8*>(&Bsh[swzA(row, seg)]) =
          *reinterpret_cast<const short8*>(Wihb + (size_t)row * 128 + ks2 * 64 + seg * 8);
    }
    __syncthreads();
    #pragma unroll
    for (int ks = 0; ks < 2; ++ks) {
      int m = m0 + r0 + lr;
      int kof = ks2 * 64 + ks * 32 + lq * 8;
      short8 a;
      if (m < M) {
        const float4* p = reinterpret_cast<const float4*>(hf + (size_t)m * 128 + kof);
        const float4* t = reinterpret_cast<const float4*>(te + kof);
        float4 x0 = p[0], x1 = p[1], t0 = t[0], t1 = t[1];
        a[0]=(short)f2bf(x0.x+t0.x); a[1]=(short)f2bf(x0.y+t0.y);
        a[2]=(short)f2bf(x0.z+t0.z); a[3]=(short)f2bf(x0.w+t0.w);
        a[4]=(short)f2bf(x1.x+t1.x); a[5]=(short)f2bf(x1.y+t1.y);
        a[6]=(short)f2bf(x1.z+t1.z); a[7]=(short)f2bf(x1.w+t1.w);
      } else {
        #pragma unroll
        for (int j = 0; j < 8; ++j) a[j] = 0;
      }
      #pragma unroll
      for (int s = 0; s < 3; ++s)
        #pragma unroll
        for (int xi = 0; xi < 4; ++xi) {
          short8 b = *reinterpret_cast<const short8*>(
              &Bsh[swzA(s*128 + c0 + xi*16 + lr, ks*4 + lq)]);
          acc[s][xi] = __builtin_amdgcn_mfma_f32_16x16x32_bf16(a, b, acc[s][xi], 0, 0, 0);
        }
    }
  }
  // GRU epilogue
  #pragma unroll
  for (int xi = 0; xi < 4; ++xi) {
    int x = c0 + xi * 16 + lr;
    float br = b_ih[x], bz = b_ih[128 + x], bn = b_ih[256 + x];
    #pragma unroll
    for (int rr = 0; rr < 4; ++rr) {
      int m = m0 + r0 + lq * 4 + rr;
      if (m >= M) continue;
      int node = m >> 3;
      float ghr = bf2f(ghb[(size_t)node * 384 + x]);
      float ghz = bf2f(ghb[(size_t)node * 384 + 128 + x]);
      float ghn = bf2f(ghb[(size_t)node * 384 + 256 + x]);
      float mem = bf2f(memb[(size_t)node * 128 + x]);
      float rv = sigm(acc[0][xi][rr] + br + ghr);
      float zv = sigm(acc[1][xi][rr] + bz + ghz);
      float nv = tanhf(acc[2][xi][rr] + bn + rv * ghn);
      hnb[(size_t)m * 128 + x] = f2bf((1.f - zv) * nv + zv * mem);
    }
  }
}

// ---------------- pooled partial sums ----------------
__global__ __launch_bounds__(256) void k_pool(const ushortT* __restrict__ hnb,
                                              float* __restrict__ prw, int N)
{
  int tid = threadIdx.x;
  float acc[4] = {0.f, 0.f, 0.f, 0.f};
  for (int n = blockIdx.x; n < N; n += gridDim.x) {
    const ushortT* row = hnb + (size_t)n * 1024;
    #pragma unroll
    for (int j = 0; j < 4; ++j) acc[j] += bf2f(row[tid + j * 256]);
  }
  #pragma unroll
  for (int j = 0; j < 4; ++j) atomicAdd(&prw[tid + j * 256], acc[j]);
}

// ---------------- CSR build ----------------
__global__ void k_hist(const int* __restrict__ srcI, int* __restrict__ cnt, int E)
{
  int e = blockIdx.x * 256 + threadIdx.x;
  if (e < E) atomicAdd(&cnt[srcI[e]], 1);
}

__global__ __launch_bounds__(1024) void k_scan(const int* __restrict__ cnt,
    int* __restrict__ ofs, int* __restrict__ cur, int N)
{
  __shared__ int buf[1024];
  __shared__ int carry;
  int tid = threadIdx.x;
  if (tid == 0) carry = 0;
  __syncthreads();
  for (int base = 0; base < N; base += 1024) {
    int i = base + tid;
    int v = (i < N) ? cnt[i] : 0;
    buf[tid] = v;
    __syncthreads();
    for (int off = 1; off < 1024; off <<= 1) {
      int t = (tid >= off) ? buf[tid - off] : 0;
      __syncthreads();
      buf[tid] += t;
      __syncthreads();
    }
    int excl = carry + buf[tid] - v;
    if (i < N) { ofs[i] = excl; cur[i] = excl; }
    __syncthreads();
    if (tid == 0) carry += buf[1023];
    __syncthreads();
  }
  if (tid == 0) ofs[N] = carry;
}

__global__ void k_fill(const int* __restrict__ srcI, int* __restrict__ cur,
                       int* __restrict__ eid, int E)
{
  int e = blockIdx.x * 256 + threadIdx.x;
  if (e >= E) return;
  int p = atomicAdd(&cur[srcI[e]], 1);
  eid[p] = e;
}

// ---------------- GIN aggregation (CSR gather, bf16) ----------------
template<int LMODE>
__global__ __launch_bounds__(256) void k_agg(const ushortT* __restrict__ hb,
    const ushortT* __restrict__ eab, const float* __restrict__ ew,
    const int* __restrict__ dstI, const int* __restrict__ ofs,
    const int* __restrict__ eid, ushortT* __restrict__ aggb, int N)
{
  int half = threadIdx.x >> 7;
  int x = threadIdx.x & 127;
  int n = blockIdx.x * 2 + half;
  if (n >= N) return;
  float acc[8] = {};
  int beg = ofs[n], end = ofs[n + 1];
  for (int i = beg; i < end; ++i) {
    int e = eid[i];
    int d = dstI[e];
    float eav = bf2f(eab[(size_t)e * 128 + x]);
    const float* ewp = ew + (size_t)e * 8;
    if (LMODE == 1) {
      float m = fmaxf(bf2f(hb[(size_t)d * 128 + x]) + eav, 0.f);
      #pragma unroll
      for (int v = 0; v < 8; ++v) acc[v] += m * ewp[v];
    } else {
      const ushortT* hd = hb + (size_t)d * 1024;
      #pragma unroll
      for (int v = 0; v < 8; ++v)
        acc[v] += fmaxf(bf2f(hd[v * 128 + x]) + eav, 0.f) * ewp[v];
    }
  }
  ushortT* ag = aggb + (size_t)n * 1024;
  #pragma unroll
  for (int v = 0; v < 8; ++v) ag[v * 128 + x] = f2bf(acc[v]);
}

// ---------------- edge gate ----------------
__global__ __launch_bounds__(256) void k_ew(const ushortT* __restrict__ eab,
    const ushortT* __restrict__ memb, const int* __restrict__ srcI,
    const float* __restrict__ W_ewg, const float* __restrict__ b_ewg,
    float* __restrict__ ew, int E)
{
  __shared__ float Wsh[2048];
  __shared__ float bsh[8];
  int tid = threadIdx.x;
  for (int i = tid; i < 2048; i += 256) Wsh[i] = W_ewg[i];
  if (tid < 8) bsh[tid] = b_ewg[tid];
  __syncthreads();
  int wv = tid >> 6, lane = tid & 63;
  int e = blockIdx.x * 4 + wv;
  if (e >= E) return;
  int s = srcI[e];
  float c0 = bf2f(eab[(size_t)e * 128 + lane]);
  float c1 = bf2f(eab[(size_t)e * 128 + 64 + lane]);
  float c2 = bf2f(memb[(size_t)s * 128 + lane]);
  float c3 = bf2f(memb[(size_t)s * 128 + 64 + lane]);
  #pragma unroll
  for (int v = 0; v < 8; ++v) {
    float p = c0 * Wsh[v * 256 + lane] + c1 * Wsh[v * 256 + 64 + lane]
            + c2 * Wsh[v * 256 + 128 + lane] + c3 * Wsh[v * 256 + 192 + lane];
    #pragma unroll
    for (int o = 32; o; o >>= 1) p += __shfl_down(p, o);
    if (lane == 0) ew[(size_t)e * 8 + v] = sigm(p + bsh[v]);
  }
}

// ---------------- multi-tensor f32 -> bf16 ----------------
__global__ void k_cvtall(const float* __restrict__ s0, ushortT* __restrict__ d0, int n0,
                         const float* __restrict__ s1, ushortT* __restrict__ d1, int n1,
                         const float* __restrict__ s2, ushortT* __restrict__ d2, int n2,
                         const float* __restrict__ s3, ushortT* __restrict__ d3, int n3)
{
  int i = blockIdx.x * 256 + threadIdx.x;
  if (i < n0) { d0[i] = f2bf(s0[i]); return; }
  i -= n0;
  if (i < n1) { d1[i] = f2bf(s1[i]); return; }
  i -= n1;
  if (i < n2) { d2[i] = f2bf(s2[i]); return; }
  i -= n2;
  if (i < n3) d3[i] = f2bf(s3[i]);
}

// ---------------- fused small mats + te ----------------
__global__ __launch_bounds__(256) void k_prep(
    const float* __restrict__ Wo_l, const float* __restrict__ Wv_l,
    const float* __restrict__ bv_l, const float* __restrict__ bo_l,
    const float* __restrict__ Wq_l, const float* __restrict__ bq_l,
    const float* __restrict__ Wk_l,
    const float* __restrict__ delta_t, const float* __restrict__ W_t,
    const float* __restrict__ b_t,
    float* __restrict__ Wl2f, float* __restrict__ blv,
    ushortT* __restrict__ Wqkgb, float* __restrict__ bqkg, float* __restrict__ te)
{
  int idx = blockIdx.x * 256 + threadIdx.x;    // 65536 total
  if (idx < 32768) {
    int n = idx >> 8, k = idx & 255;
    float a = 0.f;
    for (int j = 0; j < 128; ++j) a += Wo_l[n * 128 + j] * Wv_l[j * 256 + k];
    Wl2f[idx] = a;
  } else {
    int rem = idx - 32768;
    int n = rem >> 7, j = rem & 127;
    float a = 0.f;
    for (int k = 0; k < 128; ++k) a += Wq_l[k * 128 + j] * Wk_l[k * 256 + n];
    Wqkgb[rem] = f2bf(a);
  }
  if (blockIdx.x == 0 && threadIdx.x < 128) {
    int n = threadIdx.x;
    float a = bo_l[n];
    for (int j = 0; j < 128; ++j) a += Wo_l[n * 128 + j] * bv_l[j];
    blv[n] = a;
  }
  if (blockIdx.x == 1) {
    int n = threadIdx.x;
    float a = 0.f;
    for (int k = 0; k < 128; ++k) a += bq_l[k] * Wk_l[k * 256 + n];
    bqkg[n] = a;
  }
  if (blockIdx.x == 2 && threadIdx.x < 128) {
    int t = threadIdx.x;
    te[t] = sinf(delta_t[0] * W_t[t] + b_t[t]);
  }
}

// ---------------- classifier weight fusion ----------------
__global__ __launch_bounds__(256) void k_prep2(
    const float* __restrict__ Wc1, const float* __restrict__ bc1,
    const float* __restrict__ Wl2f, const float* __restrict__ blv,
    ushortT* __restrict__ Wc1p, float* __restrict__ bc1p)
{
  int idx = blockIdx.x * 256 + threadIdx.x;    // 65536 total
  int n = idx >> 9, k = idx & 511;
  float a;
  if (k < 128) a = Wc1[(size_t)n * 384 + k];
  else if (k < 384) {
    int kk = k - 128;
    a = 0.f;
    for (int j = 0; j < 128; ++j) a += Wc1[(size_t)n * 384 + 128 + j] * Wl2f[j * 256 + kk];
  } else a = Wc1[(size_t)n * 384 + 256 + (k - 384)];
  Wc1p[idx] = f2bf(a);
  if (blockIdx.x == 0 && threadIdx.x < 128) {
    int nn = threadIdx.x;
    float b = bc1[nn];
    for (int j = 0; j < 128; ++j) b += Wc1[(size_t)nn * 384 + 128 + j] * blv[j];
    bc1p[nn] = b;
  }
}

// ---------------- Kg / G for global attention ----------------
__global__ __launch_bounds__(256) void k_kgg(const float* __restrict__ prw,
    const float* __restrict__ Wk_g, const float* __restrict__ Wv_g, const float* __restrict__ bv_g,
    const float* __restrict__ Wo_g, float* __restrict__ Kg, float* __restrict__ G, int N)
{
  __shared__ float pl[1024];
  __shared__ float vg[1024];
  int tid = threadIdx.x;
  float invN = 1.f / (float)N;
  for (int i = tid; i < 1024; i += 256) pl[i] = prw[i] * invN;
  __syncthreads();
  for (int o = tid; o < 1024; o += 256) {
    int v = o >> 7, x = o & 127;
    float a = 0.f, b = 0.f;
    for (int k = 0; k < 128; ++k) {
      float p = pl[v * 128 + k];
      a += p * Wk_g[(size_t)x * 128 + k];
      b += p * Wv_g[(size_t)x * 128 + k];
    }
    Kg[o] = a;
    vg[o] = b + bv_g[x];
  }
  __syncthreads();
  for (int o = tid; o < 1024; o += 256) {
    int v = o >> 7, x = o & 127;
    float a = 0.f;
    for (int k = 0; k < 128; ++k) a += vg[v * 128 + k] * Wo_g[(size_t)x * 128 + k];
    G[o] = a;
  }
}

// ---------------- global-score projection rows ----------------
__global__ __launch_bounds__(256) void k_sc(const float* __restrict__ Kg,
    const float* __restrict__ Wq_g, const float* __restrict__ bq_g,
    ushortT* __restrict__ Wqkgb, float* __restrict__ bqkg)
{
  int idx = blockIdx.x * 256 + threadIdx.x;    // 1024
  int v = idx >> 7, j = idx & 127;
  float a = 0.f;
  for (int x = 0; x < 128; ++x) a += Kg[v * 128 + x] * Wq_g[(size_t)x * 128 + j];
  Wqkgb[(size_t)(256 + v) * 128 + j] = f2bf(a);
  if (blockIdx.x == 0 && threadIdx.x < 8) {
    int vv = threadIdx.x;
    float b = 0.f;
    for (int x = 0; x < 128; ++x) b += bq_g[x] * Kg[vv * 128 + x];
    bqkg[256 + vv] = b;
  }
}

// ---------------- fused local+global attention: 2 edges/wave ----------------
__global__ __launch_bounds__(256) void k_lg(
    const ushortT* __restrict__ hnb, const ushortT* __restrict__ qkgb,
    const int* __restrict__ srcI, const int* __restrict__ dstI,
    const float* __restrict__ G, const float* __restrict__ bo_g,
    float* __restrict__ ag_out, ushortT* __restrict__ wsd,
    ushortT* __restrict__ glbb, int E)
{
  __shared__ float Gs[1024], bsh[128];
  int tid = threadIdx.x;
  for (int i = tid; i < 1024; i += 256) Gs[i] = G[i];
  if (tid < 128) bsh[tid] = bo_g[tid];
  __syncthreads();
  int w = tid >> 6, l = tid & 63, half = l >> 5, l31 = l & 31;
  int e = blockIdx.x * 8 + w * 2 + half;
  int ec = (e < E) ? e : (E - 1);
  int s = srcI[ec], d = dstI[ec];
  const uint2* qrow = reinterpret_cast<const uint2*>(qkgb + (size_t)ec * 264);
  uint2 q1u = qrow[l31], q2u = qrow[32 + l31];
  uint4 scu = *reinterpret_cast<const uint4*>(qkgb + (size_t)ec * 264 + 256);
  const uint2* srow = reinterpret_cast<const uint2*>(hnb + (size_t)s * 1024);
  const uint2* drow = reinterpret_cast<const uint2*>(hnb + (size_t)d * 1024);
  uint2 su[8], du[8];
  #pragma unroll
  for (int v = 0; v < 8; ++v) { su[v] = srow[v * 32 + l31]; du[v] = drow[v * 32 + l31]; }
  float q1f[4] = {bflo(q1u.x), bfhi(q1u.x), bflo(q1u.y), bfhi(q1u.y)};
  float q2f[4] = {bflo(q2u.x), bfhi(q2u.x), bflo(q2u.y), bfhi(q2u.y)};
  float pl[8];
  #pragma unroll
  for (int v = 0; v < 8; ++v) {
    pl[v] = q1f[0] * bflo(su[v].x) + q1f[1] * bfhi(su[v].x)
          + q1f[2] * bflo(su[v].y) + q1f[3] * bfhi(su[v].y)
          + q2f[0] * bflo(du[v].x) + q2f[1] * bfhi(du[v].x)
          + q2f[2] * bflo(du[v].y) + q2f[3] * bfhi(du[v].y);
  }
  #pragma unroll
  for (int v = 0; v < 8; ++v) {
    #pragma unroll
    for (int m = 1; m <= 16; m <<= 1) pl[v] += __shfl_xor(pl[v], m);
  }
  const float scale = 0.08838834764831845f;   // 1/sqrt(128)
  float mx = fmaxf(fmaxf(fmaxf(pl[0], pl[1]), fmaxf(pl[2], pl[3])),
                   fmaxf(fmaxf(pl[4], pl[5]), fmaxf(pl[6], pl[7])));
  float suml = 0.f, al[8];
  #pragma unroll
  for (int v = 0; v < 8; ++v) { al[v] = __expf((pl[v] - mx) * scale); suml += al[v]; }
  float invl = 1.f / suml;
  float ws0 = 0.f, ws1 = 0.f, ws2 = 0.f, ws3 = 0.f;
  float wd0 = 0.f, wd1 = 0.f, wd2 = 0.f, wd3 = 0.f;
  #pragma unroll
  for (int v = 0; v < 8; ++v) {
    float a = al[v];
    ws0 += a * bflo(su[v].x); ws1 += a * bfhi(su[v].x);
    ws2 += a * bflo(su[v].y); ws3 += a * bfhi(su[v].y);
    wd0 += a * bflo(du[v].x); wd1 += a * bfhi(du[v].x);
    wd2 += a * bflo(du[v].y); wd3 += a * bfhi(du[v].y);
  }
  if (e < E) {
    uint2* wrow = reinterpret_cast<uint2*>(wsd + (size_t)e * 256);
    uint2 t0; t0.x = pk2bf(ws0 * invl, ws1 * invl); t0.y = pk2bf(ws2 * invl, ws3 * invl);
    uint2 t1; t1.x = pk2bf(wd0 * invl, wd1 * invl); t1.y = pk2bf(wd2 * invl, wd3 * invl);
    wrow[l31] = t0;
    wrow[32 + l31] = t1;
  }
  float sg[8] = {bflo(scu.x), bfhi(scu.x), bflo(scu.y), bfhi(scu.y),
                 bflo(scu.z), bfhi(scu.z), bflo(scu.w), bfhi(scu.w)};
  float mg = fmaxf(fmaxf(fmaxf(sg[0], sg[1]), fmaxf(sg[2], sg[3])),
                   fmaxf(fmaxf(sg[4], sg[5]), fmaxf(sg[6], sg[7])));
  float sumg = 0.f, ag[8];
  #pragma unroll
  for (int v = 0; v < 8; ++v) { ag[v] = __expf((sg[v] - mg) * scale); sumg += ag[v]; }
  float invg = 1.f / sumg;
  if (e < E && l31 < 8) ag_out[(size_t)e * 8 + l31] = ag[l31] * invg;
  float4 b4 = *reinterpret_cast<const float4*>(&bsh[4 * l31]);
  float g0 = b4.x, g1 = b4.y, g2 = b4.z, g3 = b4.w;
  #pragma unroll
  for (int v = 0; v < 8; ++v) {
    float sv = ag[v] * invg;
    float4 gv = *reinterpret_cast<const float4*>(&Gs[v * 128 + 4 * l31]);
    g0 += sv * gv.x; g1 += sv * gv.y; g2 += sv * gv.z; g3 += sv * gv.w;
  }
  if (e < E) {
    uint2 t; t.x = pk2bf(g0, g1); t.y = pk2bf(g2, g3);
    reinterpret_cast<uint2*>(glbb + (size_t)e * 128)[l31] = t;
  }
}

// ---------------- logits ----------------
__global__ __launch_bounds__(256) void k_logits(const ushortT* __restrict__ hid,
    const float* __restrict__ Wc2, const float* __restrict__ bc2,
    float* __restrict__ logits, int E)
{
  __shared__ float Wsh[640];
  __shared__ float bsh[5];
  int tid = threadIdx.x;
  for (int i = tid; i < 640; i += 256) Wsh[i] = Wc2[i];
  if (tid < 5) bsh[tid] = bc2[tid];
  __syncthreads();
  int wv = tid >> 6, lane = tid & 63;
  int e = blockIdx.x * 4 + wv;
  if (e >= E) return;
  float h0 = bf2f(hid[(size_t)e * 128 + lane]), h1 = bf2f(hid[(size_t)e * 128 + 64 + lane]);
  #pragma unroll
  for (int c = 0; c < 5; ++c) {
    float p = h0 * Wsh[c * 128 + lane] + h1 * Wsh[c * 128 + 64 + lane];
    #pragma unroll
    for (int o = 32; o; o >>= 1) p += __shfl_down(p, o);
    if (lane == 0) logits[(size_t)e * 5 + c] = p + bsh[c];
  }
}

extern "C" void kernel_launch(void* const* d_in, const int* in_sizes, int n_in,
                              void* d_out, int out_size, void* d_ws, size_t ws_size,
                              hipStream_t stream)
{
  const int*   edge_index = (const int*)d_in[0];
  const float* edge_attr  = (const float*)d_in[1];
  const float* delta_t    = (const float*)d_in[2];
  const float* memory     = (const float*)d_in[3];
  const float* W_ee  = (const float*)d_in[4];
  const float* b_ee  = (const float*)d_in[5];
  const float* W_ewg = (const float*)d_in[6];
  const float* b_ewg = (const float*)d_in[7];
  const float* gin_W1 = (const float*)d_in[8];
  const float* gin_b1 = (const float*)d_in[9];
  const float* gin_W2 = (const float*)d_in[10];
  const float* gin_b2 = (const float*)d_in[11];
  const float* W_t  = (const float*)d_in[12];
  const float* b_t  = (const float*)d_in[13];
  const float* W_ih = (const float*)d_in[14];
  const float* b_ih = (const float*)d_in[15];
  const float* W_hh = (const float*)d_in[16];
  const float* b_hh = (const float*)d_in[17];
  const float* Wq_l = (const float*)d_in[20];
  const float* bq_l = (const float*)d_in[21];
  const float* Wk_l = (const float*)d_in[22];
  const float* Wv_l = (const float*)d_in[24];
  const float* bv_l = (const float*)d_in[25];
  const float* Wo_l = (const float*)d_in[26];
  const float* bo_l = (const float*)d_in[27];
  const float* Wq_g = (const float*)d_in[28];
  const float* bq_g = (const float*)d_in[29];
  const float* Wk_g = (const float*)d_in[30];
  const float* Wv_g = (const float*)d_in[32];
  const float* bv_g = (const float*)d_in[33];
  const float* Wo_g = (const float*)d_in[34];
  const float* bo_g = (const float*)d_in[35];
  const float* Wc1  = (const float*)d_in[36];
  const float* bc1  = (const float*)d_in[37];
  const float* Wc2  = (const float*)d_in[38];
  const float* bc2  = (const float*)d_in[39];

  const int E = in_sizes[0] / 2;
  const int N = in_sizes[3] / HSZ;
  const int* srcI = edge_index;
  const int* dstI = edge_index + E;

  float* out    = (float*)d_out;
  float* logits = out;
  float* ew     = out + (size_t)E * 5;
  float* h      = out + (size_t)E * 13;                       // h_before (N,8,128) f32
  float* ag_out = out + (size_t)E * 13 + (size_t)N * 1024;

  // ---- workspace arena (units: f32 slots) ----
  float* ws = (float*)d_ws;
  size_t off = 0;
  auto alloc = [&](size_t n) { size_t o = off; off += (n + 255) & ~(size_t)255; return o; };
  float* te   = ws + alloc(128);
  float* blv  = ws + alloc(128);
  float* bqkg = ws + alloc(384);
  float* bc1p = ws + alloc(128);
  float* Kg   = ws + alloc(1024);
  float* G    = ws + alloc(1024);
  float* prw  = ws + alloc(1024);
  int* cnt = (int*)(ws + alloc(N));
  int* ofs = (int*)(ws + alloc(N + 1));
  int* cur = (int*)(ws + alloc(N));
  int* eid = (int*)(ws + alloc(E));
  ushortT* memb   = (ushortT*)(ws + alloc((size_t)N * 64));
  ushortT* eab    = (ushortT*)(ws + alloc((size_t)E * 64));
  ushortT* h1b    = (ushortT*)(ws + alloc((size_t)N * 512));
  ushortT* hnb    = (ushortT*)(ws + alloc((size_t)N * 512));
  ushortT* ghb    = (ushortT*)(ws + alloc((size_t)N * 192));
  ushortT* ginW1b = (ushortT*)(ws + alloc(16384));
  ushortT* ginW2b = (ushortT*)(ws + alloc(16384));
  ushortT* Wihb   = (ushortT*)(ws + alloc(24576));
  float*   Wl2f   = ws + alloc(32768);
  ushortT* Wc1p   = (ushortT*)(ws + alloc(32768));   // 128 x 512 bf16
  ushortT* Wqkgb  = (ushortT*)(ws + alloc(16896));   // 264 x 128 bf16
  // BR union: aggb (N*512) | attn {qkgb 132E | wsd 128E | glbb 64E} (324E)
  size_t brA = (size_t)N * 512, brC = (size_t)E * 324;
  size_t brsz = brA > brC ? brA : brC;
  float* BR = ws + alloc(brsz);
  if (ws_size < off * sizeof(float)) return;   // needs ~130 MiB

  ushortT* aggb = (ushortT*)BR;
  ushortT* qkgb = (ushortT*)BR;                        // E x 264
  ushortT* wsd  = (ushortT*)(BR + (size_t)E * 132);    // E x 256
  ushortT* glbb = (ushortT*)(BR + (size_t)E * 260);    // E x 128
  ushortT* hid  = (ushortT*)BR;                        // E x 128 (over dead qkgb)

  auto cdiv = [](int a, int b) { return (a + b - 1) / b; };

  // 0. CSR + bf16 mirrors/weights + zero pool accumulator
  hipMemsetAsync(cnt, 0, (size_t)N * sizeof(int), stream);
  hipMemsetAsync(prw, 0, 1024 * sizeof(float), stream);
  k_hist<<<cdiv(E, 256), 256, 0, stream>>>(srcI, cnt, E);
  k_scan<<<1, 1024, 0, stream>>>(cnt, ofs, cur, N);
  k_fill<<<cdiv(E, 256), 256, 0, stream>>>(srcI, cur, eid, E);
  {
    int total = N * 128 + 32768 + 32768 + 49152;
    k_cvtall<<<cdiv(total, 256), 256, 0, stream>>>(
        memory, memb, N * 128, gin_W1, ginW1b, 32768,
        gin_W2, ginW2b, 32768, W_ih, Wihb, 49152);
  }
  // 1. ea = relu(edge_attr @ W_ee^T + b_ee) -> bf16
  gemm_bf<0, 1, true, false, false><<<dim3(cdiv(E, 128), 1), 256, 0, stream>>>(
      edge_attr, nullptr, nullptr, W_ee, b_ee, eab, E, 59, 128);
  // 2. ew + prep(+te) + prep2 + gh
  k_ew<<<cdiv(E, 4), 256, 0, stream>>>(eab, memb, srcI, W_ewg, b_ewg, ew, E);
  k_prep<<<256, 256, 0, stream>>>(Wo_l, Wv_l, bv_l, bo_l, Wq_l, bq_l, Wk_l,
                                  delta_t, W_t, b_t, Wl2f, blv, Wqkgb, bqkg, te);
  k_prep2<<<256, 256, 0, stream>>>(Wc1, bc1, Wl2f, blv, Wc1p, bc1p);
  gemm_bf<0, 0, true, false, false><<<dim3(cdiv(N, 128), 3), 256, 0, stream>>>(
      memory, nullptr, nullptr, W_hh, b_hh, ghb, N, 128, 384);
  // 3. GIN layer 1 (h == broadcast memory)
  k_agg<1><<<cdiv(N, 2), 256, 0, stream>>>(memb, eab, ew, dstI, ofs, eid, aggb, N);
  k_gin<1><<<cdiv(N * 8, 64), 256, 0, stream>>>(
      memb, aggb, nullptr, h1b, ginW1b, gin_b1, ginW2b, gin_b2, N * 8);
  // 4. GIN layer 2 -> h (d_out f32)
  k_agg<2><<<cdiv(N, 2), 256, 0, stream>>>(h1b, eab, ew, dstI, ofs, eid, aggb, N);
  k_gin<2><<<cdiv(N * 8, 64), 256, 0, stream>>>(
      h1b, aggb, h, nullptr, ginW1b + 16384, gin_b1 + 128,
      ginW2b + 16384, gin_b2 + 128, N * 8);
  // 5. fused gi GEMM + GRU -> hnb; pooled partials separately
  k_giru<<<cdiv(N * 8, 64), 512, 0, stream>>>(h, te, Wihb, b_ih, ghb, memb, hnb, N * 8);
  k_pool<<<256, 256, 0, stream>>>(hnb, prw, N);
  // 6. global K/G + score-projection rows
  k_kgg<<<1, 256, 0, stream>>>(prw, Wk_g, Wv_g, bv_g, Wo_g, Kg, G, N);
  k_sc<<<4, 256, 0, stream>>>(Kg, Wq_g, bq_g, Wqkgb, bqkg);
  // 7. fused q projections + global scores (Nout=264)
  gemm_bf<0, 0, true, true, true><<<dim3(cdiv(E, 128), 3), 256, 0, stream>>>(
      eab, nullptr, nullptr, Wqkgb, bqkg, qkgb, E, 128, 264);
  // 8. fused local+global attention (2 edges/wave)
  k_lg<<<cdiv(E, 8), 256, 0, stream>>>(hnb, qkgb, srcI, dstI, G, bo_g,
                                       ag_out, wsd, glbb, E);
  // 9. classifier (localout folded in): K=512 over {ea, wsd, glbb}
  gemm_bf<4, 1, true, true, true><<<dim3(cdiv(E, 128), 1), 256, 0, stream>>>(
      eab, wsd, glbb, Wc1p, bc1p, hid, E, 512, 128);
  k_logits<<<cdiv(E, 4), 256, 0, stream>>>(hid, Wc2, bc2, logits, E);
}

// Round 11
// 524.586 us; speedup vs baseline: 1.0025x; 1.0025x over previous
//
#include <hip/hip_runtime.h>
#include <cstddef>

// MVMGIN round 11:
//  - k_gin: revert BM=128 (round-10 BM=64 doubled weight traffic, regressed);
//    instead 512 threads / 8 waves per block (each wave owns 32x64) — same
//    traffic, 2x resident waves to hide the direct-A-load latency.
// Carried: k_giru B-in-LDS/A-direct; weights direct (L1-resident) in k_gin;
// separate k_pool; global scores folded into qkg GEMM; classifier K=512 fusion;
// 2-edge/wave k_lg; CSR gather; bf16 everywhere; q_l/Wl2/blv foldings.
// Outputs (f32, concat): logits(E,5) | ew(E,8) | h_before(N,8,128) | a_g(E,8)

#define HSZ 128
typedef unsigned short ushortT;
typedef unsigned int uintT;
typedef short short8 __attribute__((ext_vector_type(8)));
typedef float f32x4 __attribute__((ext_vector_type(4)));

__device__ __forceinline__ float sigm(float x) { return 1.f / (1.f + __expf(-x)); }

__device__ __forceinline__ ushortT f2bf(float f) {
  unsigned int u = __float_as_uint(f);
  u += 0x7fffu + ((u >> 16) & 1u);
  return (ushortT)(u >> 16);
}
__device__ __forceinline__ float bf2f(ushortT u) {
  return __uint_as_float(((unsigned int)u) << 16);
}
__device__ __forceinline__ float bflo(uintT u) { return __uint_as_float(u << 16); }
__device__ __forceinline__ float bfhi(uintT u) { return __uint_as_float(u & 0xffff0000u); }
__device__ __forceinline__ uintT pk2bf(float a, float b) {
  return ((uintT)f2bf(b) << 16) | (uintT)f2bf(a);
}

// XOR-swizzled LDS chunk index (in shorts): row stride 64 shorts.
__device__ __forceinline__ int swzA(int row, int chunk) {
  return row * 64 + (((chunk ^ row) & 7) << 3);
}
__device__ __forceinline__ int swzT(int row, int chunk) {
  return row * 128 + (((chunk & 8) | ((chunk ^ row) & 7)) << 3);
}

// ---------------- bf16 MFMA GEMM (generic, LDS-staged) ----------------
// ASRC: 0=A1; 4=concat{A1(128), A2(256), A3(128)} bf16. ABF: A bf16 (K%64==0).
template<int ASRC, int ACT, bool OUTBF, bool ABF, bool WBF>
__global__ __launch_bounds__(256) void gemm_bf(
    const void* __restrict__ A1, const void* __restrict__ A2, const void* __restrict__ A3,
    const void* __restrict__ W, const float* __restrict__ bias,
    void* __restrict__ out_, int M, int K, int Nout)
{
  __shared__ short Ash[128 * 64];
  __shared__ short Bsh[128 * 64];
  float* out = (float*)out_;
  ushortT* outh = (ushortT*)out_;
  const int tid = threadIdx.x;
  const int m0 = blockIdx.x * 128;
  const int n0 = blockIdx.y * 128;
  const int l = tid & 63, w = tid >> 6;
  const int wr = w >> 1, wc = w & 1;
  const int lr = l & 15, lq = l >> 4;
  f32x4 acc[4][4] = {};

  for (int k0 = 0; k0 < K; k0 += 64) {
    __syncthreads();
    const bool fast = (k0 + 64 <= K);
    #pragma unroll
    for (int i = 0; i < 4; ++i) {
      int c = i * 256 + tid;
      int row = c >> 3, seg = c & 7;
      int kb = k0 + seg * 8;
      // ---- stage A ----
      {
        int m = m0 + row;
        short8 pk;
        if (ABF) {
          if (m < M) {
            if (ASRC == 4) {
              if (kb < 128)
                pk = *reinterpret_cast<const short8*>((const ushortT*)A1 + (size_t)m * 128 + kb);
              else if (kb < 384)
                pk = *reinterpret_cast<const short8*>((const ushortT*)A2 + (size_t)m * 256 + (kb - 128));
              else
                pk = *reinterpret_cast<const short8*>((const ushortT*)A3 + (size_t)m * 128 + (kb - 384));
            } else {
              pk = *reinterpret_cast<const short8*>((const ushortT*)A1 + (size_t)m * K + kb);
            }
          } else {
            #pragma unroll
            for (int j = 0; j < 8; ++j) pk[j] = 0;
          }
        } else {
          const float* A1f = (const float*)A1;
          float v[8];
          if (fast && m < M) {
            const float4* p = reinterpret_cast<const float4*>(A1f + (size_t)m * K + kb);
            float4 x0 = p[0], x1 = p[1];
            v[0]=x0.x; v[1]=x0.y; v[2]=x0.z; v[3]=x0.w;
            v[4]=x1.x; v[5]=x1.y; v[6]=x1.z; v[7]=x1.w;
          } else {
            #pragma unroll
            for (int j = 0; j < 8; ++j) {
              int k = kb + j;
              v[j] = (m < M && k < K) ? A1f[(size_t)m * K + k] : 0.f;
            }
          }
          #pragma unroll
          for (int j = 0; j < 8; ++j) pk[j] = (short)f2bf(v[j]);
        }
        *reinterpret_cast<short8*>(&Ash[swzA(row, seg)]) = pk;
      }
      // ---- stage B ----
      {
        int nn = n0 + row;
        short8 pk;
        if (WBF) {
          if (nn < Nout)
            pk = *reinterpret_cast<const short8*>((const ushortT*)W + (size_t)nn * K + kb);
          else {
            #pragma unroll
            for (int j = 0; j < 8; ++j) pk[j] = 0;
          }
        } else {
          const float* Wf = (const float*)W;
          float v[8];
          if (fast && nn < Nout) {
            const float4* p = reinterpret_cast<const float4*>(Wf + (size_t)nn * K + kb);
            float4 x0 = p[0], x1 = p[1];
            v[0]=x0.x; v[1]=x0.y; v[2]=x0.z; v[3]=x0.w;
            v[4]=x1.x; v[5]=x1.y; v[6]=x1.z; v[7]=x1.w;
          } else {
            #pragma unroll
            for (int j = 0; j < 8; ++j) {
              int k = kb + j;
              v[j] = (nn < Nout && k < K) ? Wf[(size_t)nn * K + k] : 0.f;
            }
          }
          #pragma unroll
          for (int j = 0; j < 8; ++j) pk[j] = (short)f2bf(v[j]);
        }
        *reinterpret_cast<short8*>(&Bsh[swzA(row, seg)]) = pk;
      }
    }
    __syncthreads();
    #pragma unroll
    for (int ks = 0; ks < 2; ++ks) {
      short8 a[4], b[4];
      #pragma unroll
      for (int mi = 0; mi < 4; ++mi)
        a[mi] = *reinterpret_cast<const short8*>(&Ash[swzA(wr*64 + mi*16 + lr, ks*4 + lq)]);
      #pragma unroll
      for (int ni = 0; ni < 4; ++ni)
        b[ni] = *reinterpret_cast<const short8*>(&Bsh[swzA(wc*64 + ni*16 + lr, ks*4 + lq)]);
      #pragma unroll
      for (int mi = 0; mi < 4; ++mi)
        #pragma unroll
        for (int ni = 0; ni < 4; ++ni)
          acc[mi][ni] = __builtin_amdgcn_mfma_f32_16x16x32_bf16(a[mi], b[ni], acc[mi][ni], 0, 0, 0);
    }
  }
  #pragma unroll
  for (int ni = 0; ni < 4; ++ni) {
    int col = n0 + wc*64 + ni*16 + lr;
    if (col >= Nout) continue;
    float bz = bias ? bias[col] : 0.f;
    #pragma unroll
    for (int mi = 0; mi < 4; ++mi) {
      int mb = m0 + wr*64 + mi*16 + lq*4;
      #pragma unroll
      for (int r = 0; r < 4; ++r) {
        int m = mb + r;
        if (m >= M) continue;
        float vv = acc[mi][ni][r] + bz;
        if (ACT == 1) vv = fmaxf(vv, 0.f);
        size_t o = (size_t)m * Nout + col;
        if (OUTBF) outh[o] = f2bf(vv); else out[o] = vv;
      }
    }
  }
}

// ---------------- fused GIN layer (BM=128, 8 waves, weights direct) ----------
// 4x2 waves: wave (wr,wc) owns rows wr*32+mi*16 (mi<2), cols wc*64+ni*16 (ni<4).
// LMODE 1: A = hb(bcast over v) + aggb; base = bf2f(hb bcast); out -> houtb bf16
// LMODE 2: A = hb + aggb;               base = bf2f(hb);       out -> houtf f32
template<int LMODE>
__global__ __launch_bounds__(512) void k_gin(
    const ushortT* __restrict__ hb, const ushortT* __restrict__ aggb,
    float* __restrict__ houtf, ushortT* __restrict__ houtb,
    const ushortT* __restrict__ W1b, const float* __restrict__ b1,
    const ushortT* __restrict__ W2b, const float* __restrict__ b2, int M)
{
  __shared__ short Tsh[16384];   // 128 x 128 bf16 (swzT), 32 KB
  const int tid = threadIdx.x;
  const int m0 = blockIdx.x * 128;
  const int l = tid & 63, w = tid >> 6;   // w = 0..7
  const int wr = w >> 1, wc = w & 1;      // wr 0..3, wc 0..1
  const int lr = l & 15, lq = l >> 4;
  f32x4 acc[2][4] = {};

  // ---- phase 1: t = (h+agg) @ W1^T  (A and B direct from global) ----
  #pragma unroll
  for (int kk = 0; kk < 4; ++kk) {
    const int kof = kk * 32 + lq * 8;
    short8 a[2], b[4];
    #pragma unroll
    for (int mi = 0; mi < 2; ++mi) {
      int m = m0 + wr*32 + mi*16 + lr;
      if (m < M) {
        short8 hv;
        if (LMODE == 1) hv = *reinterpret_cast<const short8*>(hb + ((size_t)(m >> 3)) * 128 + kof);
        else            hv = *reinterpret_cast<const short8*>(hb + (size_t)m * 128 + kof);
        short8 av = *reinterpret_cast<const short8*>(aggb + (size_t)m * 128 + kof);
        #pragma unroll
        for (int j = 0; j < 8; ++j)
          a[mi][j] = (short)f2bf(bf2f((ushortT)hv[j]) + bf2f((ushortT)av[j]));
      } else {
        #pragma unroll
        for (int j = 0; j < 8; ++j) a[mi][j] = 0;
      }
    }
    #pragma unroll
    for (int ni = 0; ni < 4; ++ni)
      b[ni] = *reinterpret_cast<const short8*>(W1b + (size_t)(wc*64 + ni*16 + lr) * 128 + kof);
    #pragma unroll
    for (int mi = 0; mi < 2; ++mi)
      #pragma unroll
      for (int ni = 0; ni < 4; ++ni)
        acc[mi][ni] = __builtin_amdgcn_mfma_f32_16x16x32_bf16(a[mi], b[ni], acc[mi][ni], 0, 0, 0);
  }
  // ---- t = relu(acc + b1) -> Tsh ----
  {
    float b1v[4];
    #pragma unroll
    for (int ni = 0; ni < 4; ++ni) b1v[ni] = b1[wc*64 + ni*16 + lr];
    #pragma unroll
    for (int mi = 0; mi < 2; ++mi)
      #pragma unroll
      for (int ni = 0; ni < 4; ++ni) {
        int col = wc*64 + ni*16 + lr;
        #pragma unroll
        for (int r = 0; r < 4; ++r) {
          int row = wr*32 + mi*16 + lq*4 + r;
          float v = fmaxf(acc[mi][ni][r] + b1v[ni], 0.f);
          Tsh[swzT(row, col >> 3) + (col & 7)] = (short)f2bf(v);
        }
      }
  }
  __syncthreads();
  // ---- phase 2: upd = t @ W2^T (B direct from global) ----
  f32x4 acc2[2][4] = {};
  #pragma unroll
  for (int kk = 0; kk < 4; ++kk) {
    const int kof = kk * 32 + lq * 8;
    short8 a[2], b[4];
    #pragma unroll
    for (int mi = 0; mi < 2; ++mi)
      a[mi] = *reinterpret_cast<const short8*>(&Tsh[swzT(wr*32 + mi*16 + lr, kk*4 + lq)]);
    #pragma unroll
    for (int ni = 0; ni < 4; ++ni)
      b[ni] = *reinterpret_cast<const short8*>(W2b + (size_t)(wc*64 + ni*16 + lr) * 128 + kof);
    #pragma unroll
    for (int mi = 0; mi < 2; ++mi)
      #pragma unroll
      for (int ni = 0; ni < 4; ++ni)
        acc2[mi][ni] = __builtin_amdgcn_mfma_f32_16x16x32_bf16(a[mi], b[ni], acc2[mi][ni], 0, 0, 0);
  }
  // ---- epilogue: out = base + upd + b2 ----
  {
    float b2v[4];
    #pragma unroll
    for (int ni = 0; ni < 4; ++ni) b2v[ni] = b2[wc*64 + ni*16 + lr];
    #pragma unroll
    for (int ni = 0; ni < 4; ++ni) {
      int col = wc*64 + ni*16 + lr;
      #pragma unroll
      for (int mi = 0; mi < 2; ++mi) {
        int mb = m0 + wr*32 + mi*16 + lq*4;
        #pragma unroll
        for (int r = 0; r < 4; ++r) {
          int m = mb + r;
          if (m >= M) continue;
          float base = (LMODE == 1) ? bf2f(hb[((size_t)(m >> 3)) * 128 + col])
                                    : bf2f(hb[(size_t)m * 128 + col]);
          float ho = base + acc2[mi][ni][r] + b2v[ni];
          if (LMODE == 1) houtb[(size_t)m * 128 + col] = f2bf(ho);
          else            houtf[(size_t)m * 128 + col] = ho;
        }
      }
    }
  }
}

// ---------------- fused gi GEMM + GRU (B staged in LDS, A direct) -------
__global__ __launch_bounds__(512) void k_giru(
    const float* __restrict__ hf, const float* __restrict__ te,
    const ushortT* __restrict__ Wihb, const float* __restrict__ b_ih,
    const ushortT* __restrict__ ghb, const ushortT* __restrict__ memb,
    ushortT* __restrict__ hnb, int M)
{
  __shared__ short Bsh[24576];    // 384 x 64 bf16 (swzA), 48 KB -> 3 blocks/CU
  const int tid = threadIdx.x;
  const int m0 = blockIdx.x * 64;
  const int l = tid & 63, w = tid >> 6;
  const int lr = l & 15, lq = l >> 4;
  const int r0 = (w >> 1) * 16, c0 = (w & 1) * 64;
  f32x4 acc[3][4] = {};

  for (int ks2 = 0; ks2 < 2; ++ks2) {
    if (ks2) __syncthreads();
    #pragma unroll
    for (int i = 0; i < 6; ++i) {           // 3072 chunks / 512 threads
      int c = i * 512 + tid;
      int row = c >> 3, seg = c & 7;
      *reinterpret_cast<short8*>(&Bsh[swzA(row, seg)]) =
          *reinterpret_cast<const short8*>(Wihb + (size_t)row * 128 + ks2 * 64 + seg * 8);
    }
    __syncthreads();
    #pragma unroll
    for (int ks = 0; ks < 2; ++ks) {
      int m = m0 + r0 + lr;
      int kof = ks2 * 64 + ks * 32 + lq * 8;
      short8 a;
      if (m < M) {
        const float4* p = reinterpret_cast<const float4*>(hf + (size_t)m * 128 + kof);
        const float4* t = reinterpret_cast<const float4*>(te + kof);
        float4 x0 = p[0], x1 = p[1], t0 = t[0], t1 = t[1];
        a[0]=(short)f2bf(x0.x+t0.x); a[1]=(short)f2bf(x0.y+t0.y);
        a[2]=(short)f2bf(x0.z+t0.z); a[3]=(short)f2bf(x0.w+t0.w);
        a[4]=(short)f2bf(x1.x+t1.x); a[5]=(short)f2bf(x1.y+t1.y);
        a[6]=(short)f2bf(x1.z+t1.z); a[7]=(short)f2bf(x1.w+t1.w);
      } else {
        #pragma unroll
        for (int j = 0; j < 8; ++j) a[j] = 0;
      }
      #pragma unroll
      for (int s = 0; s < 3; ++s)
        #pragma unroll
        for (int xi = 0; xi < 4; ++xi) {
          short8 b = *reinterpret_cast<const short8*>(
              &Bsh[swzA(s*128 + c0 + xi*16 + lr, ks*4 + lq)]);
          acc[s][xi] = __builtin_amdgcn_mfma_f32_16x16x32_bf16(a, b, acc[s][xi], 0, 0, 0);
        }
    }
  }
  // GRU epilogue
  #pragma unroll
  for (int xi = 0; xi < 4; ++xi) {
    int x = c0 + xi * 16 + lr;
    float br = b_ih[x], bz = b_ih[128 + x], bn = b_ih[256 + x];
    #pragma unroll
    for (int rr = 0; rr < 4; ++rr) {
      int m = m0 + r0 + lq * 4 + rr;
      if (m >= M) continue;
      int node = m >> 3;
      float ghr = bf2f(ghb[(size_t)node * 384 + x]);
      float ghz = bf2f(ghb[(size_t)node * 384 + 128 + x]);
      float ghn = bf2f(ghb[(size_t)node * 384 + 256 + x]);
      float mem = bf2f(memb[(size_t)node * 128 + x]);
      float rv = sigm(acc[0][xi][rr] + br + ghr);
      float zv = sigm(acc[1][xi][rr] + bz + ghz);
      float nv = tanhf(acc[2][xi][rr] + bn + rv * ghn);
      hnb[(size_t)m * 128 + x] = f2bf((1.f - zv) * nv + zv * mem);
    }
  }
}

// ---------------- pooled partial sums ----------------
__global__ __launch_bounds__(256) void k_pool(const ushortT* __restrict__ hnb,
                                              float* __restrict__ prw, int N)
{
  int tid = threadIdx.x;
  float acc[4] = {0.f, 0.f, 0.f, 0.f};
  for (int n = blockIdx.x; n < N; n += gridDim.x) {
    const ushortT* row = hnb + (size_t)n * 1024;
    #pragma unroll
    for (int j = 0; j < 4; ++j) acc[j] += bf2f(row[tid + j * 256]);
  }
  #pragma unroll
  for (int j = 0; j < 4; ++j) atomicAdd(&prw[tid + j * 256], acc[j]);
}

// ---------------- CSR build ----------------
__global__ void k_hist(const int* __restrict__ srcI, int* __restrict__ cnt, int E)
{
  int e = blockIdx.x * 256 + threadIdx.x;
  if (e < E) atomicAdd(&cnt[srcI[e]], 1);
}

__global__ __launch_bounds__(1024) void k_scan(const int* __restrict__ cnt,
    int* __restrict__ ofs, int* __restrict__ cur, int N)
{
  __shared__ int buf[1024];
  __shared__ int carry;
  int tid = threadIdx.x;
  if (tid == 0) carry = 0;
  __syncthreads();
  for (int base = 0; base < N; base += 1024) {
    int i = base + tid;
    int v = (i < N) ? cnt[i] : 0;
    buf[tid] = v;
    __syncthreads();
    for (int off = 1; off < 1024; off <<= 1) {
      int t = (tid >= off) ? buf[tid - off] : 0;
      __syncthreads();
      buf[tid] += t;
      __syncthreads();
    }
    int excl = carry + buf[tid] - v;
    if (i < N) { ofs[i] = excl; cur[i] = excl; }
    __syncthreads();
    if (tid == 0) carry += buf[1023];
    __syncthreads();
  }
  if (tid == 0) ofs[N] = carry;
}

__global__ void k_fill(const int* __restrict__ srcI, int* __restrict__ cur,
                       int* __restrict__ eid, int E)
{
  int e = blockIdx.x * 256 + threadIdx.x;
  if (e >= E) return;
  int p = atomicAdd(&cur[srcI[e]], 1);
  eid[p] = e;
}

// ---------------- GIN aggregation (CSR gather, bf16) ----------------
template<int LMODE>
__global__ __launch_bounds__(256) void k_agg(const ushortT* __restrict__ hb,
    const ushortT* __restrict__ eab, const float* __restrict__ ew,
    const int* __restrict__ dstI, const int* __restrict__ ofs,
    const int* __restrict__ eid, ushortT* __restrict__ aggb, int N)
{
  int half = threadIdx.x >> 7;
  int x = threadIdx.x & 127;
  int n = blockIdx.x * 2 + half;
  if (n >= N) return;
  float acc[8] = {};
  int beg = ofs[n], end = ofs[n + 1];
  for (int i = beg; i < end; ++i) {
    int e = eid[i];
    int d = dstI[e];
    float eav = bf2f(eab[(size_t)e * 128 + x]);
    const float* ewp = ew + (size_t)e * 8;
    if (LMODE == 1) {
      float m = fmaxf(bf2f(hb[(size_t)d * 128 + x]) + eav, 0.f);
      #pragma unroll
      for (int v = 0; v < 8; ++v) acc[v] += m * ewp[v];
    } else {
      const ushortT* hd = hb + (size_t)d * 1024;
      #pragma unroll
      for (int v = 0; v < 8; ++v)
        acc[v] += fmaxf(bf2f(hd[v * 128 + x]) + eav, 0.f) * ewp[v];
    }
  }
  ushortT* ag = aggb + (size_t)n * 1024;
  #pragma unroll
  for (int v = 0; v < 8; ++v) ag[v * 128 + x] = f2bf(acc[v]);
}

// ---------------- edge gate ----------------
__global__ __launch_bounds__(256) void k_ew(const ushortT* __restrict__ eab,
    const ushortT* __restrict__ memb, const int* __restrict__ srcI,
    const float* __restrict__ W_ewg, const float* __restrict__ b_ewg,
    float* __restrict__ ew, int E)
{
  __shared__ float Wsh[2048];
  __shared__ float bsh[8];
  int tid = threadIdx.x;
  for (int i = tid; i < 2048; i += 256) Wsh[i] = W_ewg[i];
  if (tid < 8) bsh[tid] = b_ewg[tid];
  __syncthreads();
  int wv = tid >> 6, lane = tid & 63;
  int e = blockIdx.x * 4 + wv;
  if (e >= E) return;
  int s = srcI[e];
  float c0 = bf2f(eab[(size_t)e * 128 + lane]);
  float c1 = bf2f(eab[(size_t)e * 128 + 64 + lane]);
  float c2 = bf2f(memb[(size_t)s * 128 + lane]);
  float c3 = bf2f(memb[(size_t)s * 128 + 64 + lane]);
  #pragma unroll
  for (int v = 0; v < 8; ++v) {
    float p = c0 * Wsh[v * 256 + lane] + c1 * Wsh[v * 256 + 64 + lane]
            + c2 * Wsh[v * 256 + 128 + lane] + c3 * Wsh[v * 256 + 192 + lane];
    #pragma unroll
    for (int o = 32; o; o >>= 1) p += __shfl_down(p, o);
    if (lane == 0) ew[(size_t)e * 8 + v] = sigm(p + bsh[v]);
  }
}

// ---------------- multi-tensor f32 -> bf16 ----------------
__global__ void k_cvtall(const float* __restrict__ s0, ushortT* __restrict__ d0, int n0,
                         const float* __restrict__ s1, ushortT* __restrict__ d1, int n1,
                         const float* __restrict__ s2, ushortT* __restrict__ d2, int n2,
                         const float* __restrict__ s3, ushortT* __restrict__ d3, int n3)
{
  int i = blockIdx.x * 256 + threadIdx.x;
  if (i < n0) { d0[i] = f2bf(s0[i]); return; }
  i -= n0;
  if (i < n1) { d1[i] = f2bf(s1[i]); return; }
  i -= n1;
  if (i < n2) { d2[i] = f2bf(s2[i]); return; }
  i -= n2;
  if (i < n3) d3[i] = f2bf(s3[i]);
}

// ---------------- fused small mats + te ----------------
__global__ __launch_bounds__(256) void k_prep(
    const float* __restrict__ Wo_l, const float* __restrict__ Wv_l,
    const float* __restrict__ bv_l, const float* __restrict__ bo_l,
    const float* __restrict__ Wq_l, const float* __restrict__ bq_l,
    const float* __restrict__ Wk_l,
    const float* __restrict__ delta_t, const float* __restrict__ W_t,
    const float* __restrict__ b_t,
    float* __restrict__ Wl2f, float* __restrict__ blv,
    ushortT* __restrict__ Wqkgb, float* __restrict__ bqkg, float* __restrict__ te)
{
  int idx = blockIdx.x * 256 + threadIdx.x;    // 65536 total
  if (idx < 32768) {
    int n = idx >> 8, k = idx & 255;
    float a = 0.f;
    for (int j = 0; j < 128; ++j) a += Wo_l[n * 128 + j] * Wv_l[j * 256 + k];
    Wl2f[idx] = a;
  } else {
    int rem = idx - 32768;
    int n = rem >> 7, j = rem & 127;
    float a = 0.f;
    for (int k = 0; k < 128; ++k) a += Wq_l[k * 128 + j] * Wk_l[k * 256 + n];
    Wqkgb[rem] = f2bf(a);
  }
  if (blockIdx.x == 0 && threadIdx.x < 128) {
    int n = threadIdx.x;
    float a = bo_l[n];
    for (int j = 0; j < 128; ++j) a += Wo_l[n * 128 + j] * bv_l[j];
    blv[n] = a;
  }
  if (blockIdx.x == 1) {
    int n = threadIdx.x;
    float a = 0.f;
    for (int k = 0; k < 128; ++k) a += bq_l[k] * Wk_l[k * 256 + n];
    bqkg[n] = a;
  }
  if (blockIdx.x == 2 && threadIdx.x < 128) {
    int t = threadIdx.x;
    te[t] = sinf(delta_t[0] * W_t[t] + b_t[t]);
  }
}

// ---------------- classifier weight fusion ----------------
__global__ __launch_bounds__(256) void k_prep2(
    const float* __restrict__ Wc1, const float* __restrict__ bc1,
    const float* __restrict__ Wl2f, const float* __restrict__ blv,
    ushortT* __restrict__ Wc1p, float* __restrict__ bc1p)
{
  int idx = blockIdx.x * 256 + threadIdx.x;    // 65536 total
  int n = idx >> 9, k = idx & 511;
  float a;
  if (k < 128) a = Wc1[(size_t)n * 384 + k];
  else if (k < 384) {
    int kk = k - 128;
    a = 0.f;
    for (int j = 0; j < 128; ++j) a += Wc1[(size_t)n * 384 + 128 + j] * Wl2f[j * 256 + kk];
  } else a = Wc1[(size_t)n * 384 + 256 + (k - 384)];
  Wc1p[idx] = f2bf(a);
  if (blockIdx.x == 0 && threadIdx.x < 128) {
    int nn = threadIdx.x;
    float b = bc1[nn];
    for (int j = 0; j < 128; ++j) b += Wc1[(size_t)nn * 384 + 128 + j] * blv[j];
    bc1p[nn] = b;
  }
}

// ---------------- Kg / G for global attention ----------------
__global__ __launch_bounds__(256) void k_kgg(const float* __restrict__ prw,
    const float* __restrict__ Wk_g, const float* __restrict__ Wv_g, const float* __restrict__ bv_g,
    const float* __restrict__ Wo_g, float* __restrict__ Kg, float* __restrict__ G, int N)
{
  __shared__ float pl[1024];
  __shared__ float vg[1024];
  int tid = threadIdx.x;
  float invN = 1.f / (float)N;
  for (int i = tid; i < 1024; i += 256) pl[i] = prw[i] * invN;
  __syncthreads();
  for (int o = tid; o < 1024; o += 256) {
    int v = o >> 7, x = o & 127;
    float a = 0.f, b = 0.f;
    for (int k = 0; k < 128; ++k) {
      float p = pl[v * 128 + k];
      a += p * Wk_g[(size_t)x * 128 + k];
      b += p * Wv_g[(size_t)x * 128 + k];
    }
    Kg[o] = a;
    vg[o] = b + bv_g[x];
  }
  __syncthreads();
  for (int o = tid; o < 1024; o += 256) {
    int v = o >> 7, x = o & 127;
    float a = 0.f;
    for (int k = 0; k < 128; ++k) a += vg[v * 128 + k] * Wo_g[(size_t)x * 128 + k];
    G[o] = a;
  }
}

// ---------------- global-score projection rows ----------------
__global__ __launch_bounds__(256) void k_sc(const float* __restrict__ Kg,
    const float* __restrict__ Wq_g, const float* __restrict__ bq_g,
    ushortT* __restrict__ Wqkgb, float* __restrict__ bqkg)
{
  int idx = blockIdx.x * 256 + threadIdx.x;    // 1024
  int v = idx >> 7, j = idx & 127;
  float a = 0.f;
  for (int x = 0; x < 128; ++x) a += Kg[v * 128 + x] * Wq_g[(size_t)x * 128 + j];
  Wqkgb[(size_t)(256 + v) * 128 + j] = f2bf(a);
  if (blockIdx.x == 0 && threadIdx.x < 8) {
    int vv = threadIdx.x;
    float b = 0.f;
    for (int x = 0; x < 128; ++x) b += bq_g[x] * Kg[vv * 128 + x];
    bqkg[256 + vv] = b;
  }
}

// ---------------- fused local+global attention: 2 edges/wave ----------------
__global__ __launch_bounds__(256) void k_lg(
    const ushortT* __restrict__ hnb, const ushortT* __restrict__ qkgb,
    const int* __restrict__ srcI, const int* __restrict__ dstI,
    const float* __restrict__ G, const float* __restrict__ bo_g,
    float* __restrict__ ag_out, ushortT* __restrict__ wsd,
    ushortT* __restrict__ glbb, int E)
{
  __shared__ float Gs[1024], bsh[128];
  int tid = threadIdx.x;
  for (int i = tid; i < 1024; i += 256) Gs[i] = G[i];
  if (tid < 128) bsh[tid] = bo_g[tid];
  __syncthreads();
  int w = tid >> 6, l = tid & 63, half = l >> 5, l31 = l & 31;
  int e = blockIdx.x * 8 + w * 2 + half;
  int ec = (e < E) ? e : (E - 1);
  int s = srcI[ec], d = dstI[ec];
  const uint2* qrow = reinterpret_cast<const uint2*>(qkgb + (size_t)ec * 264);
  uint2 q1u = qrow[l31], q2u = qrow[32 + l31];
  uint4 scu = *reinterpret_cast<const uint4*>(qkgb + (size_t)ec * 264 + 256);
  const uint2* srow = reinterpret_cast<const uint2*>(hnb + (size_t)s * 1024);
  const uint2* drow = reinterpret_cast<const uint2*>(hnb + (size_t)d * 1024);
  uint2 su[8], du[8];
  #pragma unroll
  for (int v = 0; v < 8; ++v) { su[v] = srow[v * 32 + l31]; du[v] = drow[v * 32 + l31]; }
  float q1f[4] = {bflo(q1u.x), bfhi(q1u.x), bflo(q1u.y), bfhi(q1u.y)};
  float q2f[4] = {bflo(q2u.x), bfhi(q2u.x), bflo(q2u.y), bfhi(q2u.y)};
  float pl[8];
  #pragma unroll
  for (int v = 0; v < 8; ++v) {
    pl[v] = q1f[0] * bflo(su[v].x) + q1f[1] * bfhi(su[v].x)
          + q1f[2] * bflo(su[v].y) + q1f[3] * bfhi(su[v].y)
          + q2f[0] * bflo(du[v].x) + q2f[1] * bfhi(du[v].x)
          + q2f[2] * bflo(du[v].y) + q2f[3] * bfhi(du[v].y);
  }
  #pragma unroll
  for (int v = 0; v < 8; ++v) {
    #pragma unroll
    for (int m = 1; m <= 16; m <<= 1) pl[v] += __shfl_xor(pl[v], m);
  }
  const float scale = 0.08838834764831845f;   // 1/sqrt(128)
  float mx = fmaxf(fmaxf(fmaxf(pl[0], pl[1]), fmaxf(pl[2], pl[3])),
                   fmaxf(fmaxf(pl[4], pl[5]), fmaxf(pl[6], pl[7])));
  float suml = 0.f, al[8];
  #pragma unroll
  for (int v = 0; v < 8; ++v) { al[v] = __expf((pl[v] - mx) * scale); suml += al[v]; }
  float invl = 1.f / suml;
  float ws0 = 0.f, ws1 = 0.f, ws2 = 0.f, ws3 = 0.f;
  float wd0 = 0.f, wd1 = 0.f, wd2 = 0.f, wd3 = 0.f;
  #pragma unroll
  for (int v = 0; v < 8; ++v) {
    float a = al[v];
    ws0 += a * bflo(su[v].x); ws1 += a * bfhi(su[v].x);
    ws2 += a * bflo(su[v].y); ws3 += a * bfhi(su[v].y);
    wd0 += a * bflo(du[v].x); wd1 += a * bfhi(du[v].x);
    wd2 += a * bflo(du[v].y); wd3 += a * bfhi(du[v].y);
  }
  if (e < E) {
    uint2* wrow = reinterpret_cast<uint2*>(wsd + (size_t)e * 256);
    uint2 t0; t0.x = pk2bf(ws0 * invl, ws1 * invl); t0.y = pk2bf(ws2 * invl, ws3 * invl);
    uint2 t1; t1.x = pk2bf(wd0 * invl, wd1 * invl); t1.y = pk2bf(wd2 * invl, wd3 * invl);
    wrow[l31] = t0;
    wrow[32 + l31] = t1;
  }
  float sg[8] = {bflo(scu.x), bfhi(scu.x), bflo(scu.y), bfhi(scu.y),
                 bflo(scu.z), bfhi(scu.z), bflo(scu.w), bfhi(scu.w)};
  float mg = fmaxf(fmaxf(fmaxf(sg[0], sg[1]), fmaxf(sg[2], sg[3])),
                   fmaxf(fmaxf(sg[4], sg[5]), fmaxf(sg[6], sg[7])));
  float sumg = 0.f, ag[8];
  #pragma unroll
  for (int v = 0; v < 8; ++v) { ag[v] = __expf((sg[v] - mg) * scale); sumg += ag[v]; }
  float invg = 1.f / sumg;
  if (e < E && l31 < 8) ag_out[(size_t)e * 8 + l31] = ag[l31] * invg;
  float4 b4 = *reinterpret_cast<const float4*>(&bsh[4 * l31]);
  float g0 = b4.x, g1 = b4.y, g2 = b4.z, g3 = b4.w;
  #pragma unroll
  for (int v = 0; v < 8; ++v) {
    float sv = ag[v] * invg;
    float4 gv = *reinterpret_cast<const float4*>(&Gs[v * 128 + 4 * l31]);
    g0 += sv * gv.x; g1 += sv * gv.y; g2 += sv * gv.z; g3 += sv * gv.w;
  }
  if (e < E) {
    uint2 t; t.x = pk2bf(g0, g1); t.y = pk2bf(g2, g3);
    reinterpret_cast<uint2*>(glbb + (size_t)e * 128)[l31] = t;
  }
}

// ---------------- logits ----------------
__global__ __launch_bounds__(256) void k_logits(const ushortT* __restrict__ hid,
    const float* __restrict__ Wc2, const float* __restrict__ bc2,
    float* __restrict__ logits, int E)
{
  __shared__ float Wsh[640];
  __shared__ float bsh[5];
  int tid = threadIdx.x;
  for (int i = tid; i < 640; i += 256) Wsh[i] = Wc2[i];
  if (tid < 5) bsh[tid] = bc2[tid];
  __syncthreads();
  int wv = tid >> 6, lane = tid & 63;
  int e = blockIdx.x * 4 + wv;
  if (e >= E) return;
  float h0 = bf2f(hid[(size_t)e * 128 + lane]), h1 = bf2f(hid[(size_t)e * 128 + 64 + lane]);
  #pragma unroll
  for (int c = 0; c < 5; ++c) {
    float p = h0 * Wsh[c * 128 + lane] + h1 * Wsh[c * 128 + 64 + lane];
    #pragma unroll
    for (int o = 32; o; o >>= 1) p += __shfl_down(p, o);
    if (lane == 0) logits[(size_t)e * 5 + c] = p + bsh[c];
  }
}

extern "C" void kernel_launch(void* const* d_in, const int* in_sizes, int n_in,
                              void* d_out, int out_size, void* d_ws, size_t ws_size,
                              hipStream_t stream)
{
  const int*   edge_index = (const int*)d_in[0];
  const float* edge_attr  = (const float*)d_in[1];
  const float* delta_t    = (const float*)d_in[2];
  const float* memory     = (const float*)d_in[3];
  const float* W_ee  = (const float*)d_in[4];
  const float* b_ee  = (const float*)d_in[5];
  const float* W_ewg = (const float*)d_in[6];
  const float* b_ewg = (const float*)d_in[7];
  const float* gin_W1 = (const float*)d_in[8];
  const float* gin_b1 = (const float*)d_in[9];
  const float* gin_W2 = (const float*)d_in[10];
  const float* gin_b2 = (const float*)d_in[11];
  const float* W_t  = (const float*)d_in[12];
  const float* b_t  = (const float*)d_in[13];
  const float* W_ih = (const float*)d_in[14];
  const float* b_ih = (const float*)d_in[15];
  const float* W_hh = (const float*)d_in[16];
  const float* b_hh = (const float*)d_in[17];
  const float* Wq_l = (const float*)d_in[20];
  const float* bq_l = (const float*)d_in[21];
  const float* Wk_l = (const float*)d_in[22];
  const float* Wv_l = (const float*)d_in[24];
  const float* bv_l = (const float*)d_in[25];
  const float* Wo_l = (const float*)d_in[26];
  const float* bo_l = (const float*)d_in[27];
  const float* Wq_g = (const float*)d_in[28];
  const float* bq_g = (const float*)d_in[29];
  const float* Wk_g = (const float*)d_in[30];
  const float* Wv_g = (const float*)d_in[32];
  const float* bv_g = (const float*)d_in[33];
  const float* Wo_g = (const float*)d_in[34];
  const float* bo_g = (const float*)d_in[35];
  const float* Wc1  = (const float*)d_in[36];
  const float* bc1  = (const float*)d_in[37];
  const float* Wc2  = (const float*)d_in[38];
  const float* bc2  = (const float*)d_in[39];

  const int E = in_sizes[0] / 2;
  const int N = in_sizes[3] / HSZ;
  const int* srcI = edge_index;
  const int* dstI = edge_index + E;

  float* out    = (float*)d_out;
  float* logits = out;
  float* ew     = out + (size_t)E * 5;
  float* h      = out + (size_t)E * 13;                       // h_before (N,8,128) f32
  float* ag_out = out + (size_t)E * 13 + (size_t)N * 1024;

  // ---- workspace arena (units: f32 slots) ----
  float* ws = (float*)d_ws;
  size_t off = 0;
  auto alloc = [&](size_t n) { size_t o = off; off += (n + 255) & ~(size_t)255; return o; };
  float* te   = ws + alloc(128);
  float* blv  = ws + alloc(128);
  float* bqkg = ws + alloc(384);
  float* bc1p = ws + alloc(128);
  float* Kg   = ws + alloc(1024);
  float* G    = ws + alloc(1024);
  float* prw  = ws + alloc(1024);
  int* cnt = (int*)(ws + alloc(N));
  int* ofs = (int*)(ws + alloc(N + 1));
  int* cur = (int*)(ws + alloc(N));
  int* eid = (int*)(ws + alloc(E));
  ushortT* memb   = (ushortT*)(ws + alloc((size_t)N * 64));
  ushortT* eab    = (ushortT*)(ws + alloc((size_t)E * 64));
  ushortT* h1b    = (ushortT*)(ws + alloc((size_t)N * 512));
  ushortT* hnb    = (ushortT*)(ws + alloc((size_t)N * 512));
  ushortT* ghb    = (ushortT*)(ws + alloc((size_t)N * 192));
  ushortT* ginW1b = (ushortT*)(ws + alloc(16384));
  ushortT* ginW2b = (ushortT*)(ws + alloc(16384));
  ushortT* Wihb   = (ushortT*)(ws + alloc(24576));
  float*   Wl2f   = ws + alloc(32768);
  ushortT* Wc1p   = (ushortT*)(ws + alloc(32768));   // 128 x 512 bf16
  ushortT* Wqkgb  = (ushortT*)(ws + alloc(16896));   // 264 x 128 bf16
  // BR union: aggb (N*512) | attn {qkgb 132E | wsd 128E | glbb 64E} (324E)
  size_t brA = (size_t)N * 512, brC = (size_t)E * 324;
  size_t brsz = brA > brC ? brA : brC;
  float* BR = ws + alloc(brsz);
  if (ws_size < off * sizeof(float)) return;   // needs ~130 MiB

  ushortT* aggb = (ushortT*)BR;
  ushortT* qkgb = (ushortT*)BR;                        // E x 264
  ushortT* wsd  = (ushortT*)(BR + (size_t)E * 132);    // E x 256
  ushortT* glbb = (ushortT*)(BR + (size_t)E * 260);    // E x 128
  ushortT* hid  = (ushortT*)BR;                        // E x 128 (over dead qkgb)

  auto cdiv = [](int a, int b) { return (a + b - 1) / b; };

  // 0. CSR + bf16 mirrors/weights + zero pool accumulator
  hipMemsetAsync(cnt, 0, (size_t)N * sizeof(int), stream);
  hipMemsetAsync(prw, 0, 1024 * sizeof(float), stream);
  k_hist<<<cdiv(E, 256), 256, 0, stream>>>(srcI, cnt, E);
  k_scan<<<1, 1024, 0, stream>>>(cnt, ofs, cur, N);
  k_fill<<<cdiv(E, 256), 256, 0, stream>>>(srcI, cur, eid, E);
  {
    int total = N * 128 + 32768 + 32768 + 49152;
    k_cvtall<<<cdiv(total, 256), 256, 0, stream>>>(
        memory, memb, N * 128, gin_W1, ginW1b, 32768,
        gin_W2, ginW2b, 32768, W_ih, Wihb, 49152);
  }
  // 1. ea = relu(edge_attr @ W_ee^T + b_ee) -> bf16
  gemm_bf<0, 1, true, false, false><<<dim3(cdiv(E, 128), 1), 256, 0, stream>>>(
      edge_attr, nullptr, nullptr, W_ee, b_ee, eab, E, 59, 128);
  // 2. ew + prep(+te) + prep2 + gh
  k_ew<<<cdiv(E, 4), 256, 0, stream>>>(eab, memb, srcI, W_ewg, b_ewg, ew, E);
  k_prep<<<256, 256, 0, stream>>>(Wo_l, Wv_l, bv_l, bo_l, Wq_l, bq_l, Wk_l,
                                  delta_t, W_t, b_t, Wl2f, blv, Wqkgb, bqkg, te);
  k_prep2<<<256, 256, 0, stream>>>(Wc1, bc1, Wl2f, blv, Wc1p, bc1p);
  gemm_bf<0, 0, true, false, false><<<dim3(cdiv(N, 128), 3), 256, 0, stream>>>(
      memory, nullptr, nullptr, W_hh, b_hh, ghb, N, 128, 384);
  // 3. GIN layer 1 (h == broadcast memory)
  k_agg<1><<<cdiv(N, 2), 256, 0, stream>>>(memb, eab, ew, dstI, ofs, eid, aggb, N);
  k_gin<1><<<cdiv(N * 8, 128), 512, 0, stream>>>(
      memb, aggb, nullptr, h1b, ginW1b, gin_b1, ginW2b, gin_b2, N * 8);
  // 4. GIN layer 2 -> h (d_out f32)
  k_agg<2><<<cdiv(N, 2), 256, 0, stream>>>(h1b, eab, ew, dstI, ofs, eid, aggb, N);
  k_gin<2><<<cdiv(N * 8, 128), 512, 0, stream>>>(
      h1b, aggb, h, nullptr, ginW1b + 16384, gin_b1 + 128,
      ginW2b + 16384, gin_b2 + 128, N * 8);
  // 5. fused gi GEMM + GRU -> hnb; pooled partials separately
  k_giru<<<cdiv(N * 8, 64), 512, 0, stream>>>(h, te, Wihb, b_ih, ghb, memb, hnb, N * 8);
  k_pool<<<256, 256, 0, stream>>>(hnb, prw, N);
  // 6. global K/G + score-projection rows
  k_kgg<<<1, 256, 0, stream>>>(prw, Wk_g, Wv_g, bv_g, Wo_g, Kg, G, N);
  k_sc<<<4, 256, 0, stream>>>(Kg, Wq_g, bq_g, Wqkgb, bqkg);
  // 7. fused q projections + global scores (Nout=264)
  gemm_bf<0, 0, true, true, true><<<dim3(cdiv(E, 128), 3), 256, 0, stream>>>(
      eab, nullptr, nullptr, Wqkgb, bqkg, qkgb, E, 128, 264);
  // 8. fused local+global attention (2 edges/wave)
  k_lg<<<cdiv(E, 8), 256, 0, stream>>>(hnb, qkgb, srcI, dstI, G, bo_g,
                                       ag_out, wsd, glbb, E);
  // 9. classifier (localout folded in): K=512 over {ea, wsd, glbb}
  gemm_bf<4, 1, true, true, true><<<dim3(cdiv(E, 128), 1), 256, 0, stream>>>(
      eab, wsd, glbb, Wc1p, bc1p, hid, E, 512, 128);
  k_logits<<<cdiv(E, 4), 256, 0, stream>>>(hid, Wc2, bc2, logits, E);
}

// Round 12
// 510.173 us; speedup vs baseline: 1.0309x; 1.0283x over previous
//
#include <hip/hip_runtime.h>
#include <cstddef>

// MVMGIN round 12: REVERT to round-9 config (measured best, 511.9 us).
//  - k_gin: BM=128, 256 threads (4 waves), Tsh-only 32KB LDS, weights direct
//    (L1-resident). Rounds 10 (BM=64) and 11 (512-thread) both regressed:
//    grid-cap starvation can't be fixed without multiplying weight traffic.
//  - k_giru: B staged in LDS (48KB), A direct; separate k_pool (atomic fanout).
// Carried: global scores folded into qkg GEMM; classifier K=512 fusion; 2-edge/wave
// k_lg; CSR gather; bf16 everywhere; q_l/Wl2/blv foldings; bk_* dropped.
// Outputs (f32, concat): logits(E,5) | ew(E,8) | h_before(N,8,128) | a_g(E,8)

#define HSZ 128
typedef unsigned short ushortT;
typedef unsigned int uintT;
typedef short short8 __attribute__((ext_vector_type(8)));
typedef float f32x4 __attribute__((ext_vector_type(4)));

__device__ __forceinline__ float sigm(float x) { return 1.f / (1.f + __expf(-x)); }

__device__ __forceinline__ ushortT f2bf(float f) {
  unsigned int u = __float_as_uint(f);
  u += 0x7fffu + ((u >> 16) & 1u);
  return (ushortT)(u >> 16);
}
__device__ __forceinline__ float bf2f(ushortT u) {
  return __uint_as_float(((unsigned int)u) << 16);
}
__device__ __forceinline__ float bflo(uintT u) { return __uint_as_float(u << 16); }
__device__ __forceinline__ float bfhi(uintT u) { return __uint_as_float(u & 0xffff0000u); }
__device__ __forceinline__ uintT pk2bf(float a, float b) {
  return ((uintT)f2bf(b) << 16) | (uintT)f2bf(a);
}

// XOR-swizzled LDS chunk index (in shorts): row stride 64 shorts.
__device__ __forceinline__ int swzA(int row, int chunk) {
  return row * 64 + (((chunk ^ row) & 7) << 3);
}
__device__ __forceinline__ int swzT(int row, int chunk) {
  return row * 128 + (((chunk & 8) | ((chunk ^ row) & 7)) << 3);
}

// ---------------- bf16 MFMA GEMM (generic, LDS-staged) ----------------
// ASRC: 0=A1; 4=concat{A1(128), A2(256), A3(128)} bf16. ABF: A bf16 (K%64==0).
template<int ASRC, int ACT, bool OUTBF, bool ABF, bool WBF>
__global__ __launch_bounds__(256) void gemm_bf(
    const void* __restrict__ A1, const void* __restrict__ A2, const void* __restrict__ A3,
    const void* __restrict__ W, const float* __restrict__ bias,
    void* __restrict__ out_, int M, int K, int Nout)
{
  __shared__ short Ash[128 * 64];
  __shared__ short Bsh[128 * 64];
  float* out = (float*)out_;
  ushortT* outh = (ushortT*)out_;
  const int tid = threadIdx.x;
  const int m0 = blockIdx.x * 128;
  const int n0 = blockIdx.y * 128;
  const int l = tid & 63, w = tid >> 6;
  const int wr = w >> 1, wc = w & 1;
  const int lr = l & 15, lq = l >> 4;
  f32x4 acc[4][4] = {};

  for (int k0 = 0; k0 < K; k0 += 64) {
    __syncthreads();
    const bool fast = (k0 + 64 <= K);
    #pragma unroll
    for (int i = 0; i < 4; ++i) {
      int c = i * 256 + tid;
      int row = c >> 3, seg = c & 7;
      int kb = k0 + seg * 8;
      // ---- stage A ----
      {
        int m = m0 + row;
        short8 pk;
        if (ABF) {
          if (m < M) {
            if (ASRC == 4) {
              if (kb < 128)
                pk = *reinterpret_cast<const short8*>((const ushortT*)A1 + (size_t)m * 128 + kb);
              else if (kb < 384)
                pk = *reinterpret_cast<const short8*>((const ushortT*)A2 + (size_t)m * 256 + (kb - 128));
              else
                pk = *reinterpret_cast<const short8*>((const ushortT*)A3 + (size_t)m * 128 + (kb - 384));
            } else {
              pk = *reinterpret_cast<const short8*>((const ushortT*)A1 + (size_t)m * K + kb);
            }
          } else {
            #pragma unroll
            for (int j = 0; j < 8; ++j) pk[j] = 0;
          }
        } else {
          const float* A1f = (const float*)A1;
          float v[8];
          if (fast && m < M) {
            const float4* p = reinterpret_cast<const float4*>(A1f + (size_t)m * K + kb);
            float4 x0 = p[0], x1 = p[1];
            v[0]=x0.x; v[1]=x0.y; v[2]=x0.z; v[3]=x0.w;
            v[4]=x1.x; v[5]=x1.y; v[6]=x1.z; v[7]=x1.w;
          } else {
            #pragma unroll
            for (int j = 0; j < 8; ++j) {
              int k = kb + j;
              v[j] = (m < M && k < K) ? A1f[(size_t)m * K + k] : 0.f;
            }
          }
          #pragma unroll
          for (int j = 0; j < 8; ++j) pk[j] = (short)f2bf(v[j]);
        }
        *reinterpret_cast<short8*>(&Ash[swzA(row, seg)]) = pk;
      }
      // ---- stage B ----
      {
        int nn = n0 + row;
        short8 pk;
        if (WBF) {
          if (nn < Nout)
            pk = *reinterpret_cast<const short8*>((const ushortT*)W + (size_t)nn * K + kb);
          else {
            #pragma unroll
            for (int j = 0; j < 8; ++j) pk[j] = 0;
          }
        } else {
          const float* Wf = (const float*)W;
          float v[8];
          if (fast && nn < Nout) {
            const float4* p = reinterpret_cast<const float4*>(Wf + (size_t)nn * K + kb);
            float4 x0 = p[0], x1 = p[1];
            v[0]=x0.x; v[1]=x0.y; v[2]=x0.z; v[3]=x0.w;
            v[4]=x1.x; v[5]=x1.y; v[6]=x1.z; v[7]=x1.w;
          } else {
            #pragma unroll
            for (int j = 0; j < 8; ++j) {
              int k = kb + j;
              v[j] = (nn < Nout && k < K) ? Wf[(size_t)nn * K + k] : 0.f;
            }
          }
          #pragma unroll
          for (int j = 0; j < 8; ++j) pk[j] = (short)f2bf(v[j]);
        }
        *reinterpret_cast<short8*>(&Bsh[swzA(row, seg)]) = pk;
      }
    }
    __syncthreads();
    #pragma unroll
    for (int ks = 0; ks < 2; ++ks) {
      short8 a[4], b[4];
      #pragma unroll
      for (int mi = 0; mi < 4; ++mi)
        a[mi] = *reinterpret_cast<const short8*>(&Ash[swzA(wr*64 + mi*16 + lr, ks*4 + lq)]);
      #pragma unroll
      for (int ni = 0; ni < 4; ++ni)
        b[ni] = *reinterpret_cast<const short8*>(&Bsh[swzA(wc*64 + ni*16 + lr, ks*4 + lq)]);
      #pragma unroll
      for (int mi = 0; mi < 4; ++mi)
        #pragma unroll
        for (int ni = 0; ni < 4; ++ni)
          acc[mi][ni] = __builtin_amdgcn_mfma_f32_16x16x32_bf16(a[mi], b[ni], acc[mi][ni], 0, 0, 0);
    }
  }
  #pragma unroll
  for (int ni = 0; ni < 4; ++ni) {
    int col = n0 + wc*64 + ni*16 + lr;
    if (col >= Nout) continue;
    float bz = bias ? bias[col] : 0.f;
    #pragma unroll
    for (int mi = 0; mi < 4; ++mi) {
      int mb = m0 + wr*64 + mi*16 + lq*4;
      #pragma unroll
      for (int r = 0; r < 4; ++r) {
        int m = mb + r;
        if (m >= M) continue;
        float vv = acc[mi][ni][r] + bz;
        if (ACT == 1) vv = fmaxf(vv, 0.f);
        size_t o = (size_t)m * Nout + col;
        if (OUTBF) outh[o] = f2bf(vv); else out[o] = vv;
      }
    }
  }
}

// ---------------- fused GIN layer (Tsh-only LDS, weights direct from L1/L2) -------
// LMODE 1: A = hb(bcast over v) + aggb; base = bf2f(hb bcast); out -> houtb bf16
// LMODE 2: A = hb + aggb;               base = bf2f(hb);       out -> houtf f32
template<int LMODE>
__global__ __launch_bounds__(256) void k_gin(
    const ushortT* __restrict__ hb, const ushortT* __restrict__ aggb,
    float* __restrict__ houtf, ushortT* __restrict__ houtb,
    const ushortT* __restrict__ W1b, const float* __restrict__ b1,
    const ushortT* __restrict__ W2b, const float* __restrict__ b2, int M)
{
  __shared__ short Tsh[16384];   // 128 x 128 bf16 (swzT), 32 KB
  const int tid = threadIdx.x;
  const int m0 = blockIdx.x * 128;
  const int l = tid & 63, w = tid >> 6;
  const int wr = w >> 1, wc = w & 1;
  const int lr = l & 15, lq = l >> 4;
  f32x4 acc[4][4] = {};

  // ---- phase 1: t = (h+agg) @ W1^T  (A and B direct from global) ----
  #pragma unroll
  for (int kk = 0; kk < 4; ++kk) {
    const int kof = kk * 32 + lq * 8;
    short8 a[4], b[4];
    #pragma unroll
    for (int mi = 0; mi < 4; ++mi) {
      int m = m0 + wr*64 + mi*16 + lr;
      if (m < M) {
        short8 hv;
        if (LMODE == 1) hv = *reinterpret_cast<const short8*>(hb + ((size_t)(m >> 3)) * 128 + kof);
        else            hv = *reinterpret_cast<const short8*>(hb + (size_t)m * 128 + kof);
        short8 av = *reinterpret_cast<const short8*>(aggb + (size_t)m * 128 + kof);
        #pragma unroll
        for (int j = 0; j < 8; ++j)
          a[mi][j] = (short)f2bf(bf2f((ushortT)hv[j]) + bf2f((ushortT)av[j]));
      } else {
        #pragma unroll
        for (int j = 0; j < 8; ++j) a[mi][j] = 0;
      }
    }
    #pragma unroll
    for (int ni = 0; ni < 4; ++ni)
      b[ni] = *reinterpret_cast<const short8*>(W1b + (size_t)(wc*64 + ni*16 + lr) * 128 + kof);
    #pragma unroll
    for (int mi = 0; mi < 4; ++mi)
      #pragma unroll
      for (int ni = 0; ni < 4; ++ni)
        acc[mi][ni] = __builtin_amdgcn_mfma_f32_16x16x32_bf16(a[mi], b[ni], acc[mi][ni], 0, 0, 0);
  }
  // ---- t = relu(acc + b1) -> Tsh ----
  {
    float b1v[4];
    #pragma unroll
    for (int ni = 0; ni < 4; ++ni) b1v[ni] = b1[wc*64 + ni*16 + lr];
    #pragma unroll
    for (int mi = 0; mi < 4; ++mi)
      #pragma unroll
      for (int ni = 0; ni < 4; ++ni) {
        int col = wc*64 + ni*16 + lr;
        #pragma unroll
        for (int r = 0; r < 4; ++r) {
          int row = wr*64 + mi*16 + lq*4 + r;
          float v = fmaxf(acc[mi][ni][r] + b1v[ni], 0.f);
          Tsh[swzT(row, col >> 3) + (col & 7)] = (short)f2bf(v);
        }
      }
  }
  __syncthreads();
  // ---- phase 2: upd = t @ W2^T (B direct from global) ----
  f32x4 acc2[4][4] = {};
  #pragma unroll
  for (int kk = 0; kk < 4; ++kk) {
    const int kof = kk * 32 + lq * 8;
    short8 a[4], b[4];
    #pragma unroll
    for (int mi = 0; mi < 4; ++mi)
      a[mi] = *reinterpret_cast<const short8*>(&Tsh[swzT(wr*64 + mi*16 + lr, kk*4 + lq)]);
    #pragma unroll
    for (int ni = 0; ni < 4; ++ni)
      b[ni] = *reinterpret_cast<const short8*>(W2b + (size_t)(wc*64 + ni*16 + lr) * 128 + kof);
    #pragma unroll
    for (int mi = 0; mi < 4; ++mi)
      #pragma unroll
      for (int ni = 0; ni < 4; ++ni)
        acc2[mi][ni] = __builtin_amdgcn_mfma_f32_16x16x32_bf16(a[mi], b[ni], acc2[mi][ni], 0, 0, 0);
  }
  // ---- epilogue: out = base + upd + b2 ----
  {
    float b2v[4];
    #pragma unroll
    for (int ni = 0; ni < 4; ++ni) b2v[ni] = b2[wc*64 + ni*16 + lr];
    #pragma unroll
    for (int ni = 0; ni < 4; ++ni) {
      int col = wc*64 + ni*16 + lr;
      #pragma unroll
      for (int mi = 0; mi < 4; ++mi) {
        int mb = m0 + wr*64 + mi*16 + lq*4;
        #pragma unroll
        for (int r = 0; r < 4; ++r) {
          int m = mb + r;
          if (m >= M) continue;
          float base = (LMODE == 1) ? bf2f(hb[((size_t)(m >> 3)) * 128 + col])
                                    : bf2f(hb[(size_t)m * 128 + col]);
          float ho = base + acc2[mi][ni][r] + b2v[ni];
          if (LMODE == 1) houtb[(size_t)m * 128 + col] = f2bf(ho);
          else            houtf[(size_t)m * 128 + col] = ho;
        }
      }
    }
  }
}

// ---------------- fused gi GEMM + GRU (B staged in LDS, A direct) -------
__global__ __launch_bounds__(512) void k_giru(
    const float* __restrict__ hf, const float* __restrict__ te,
    const ushortT* __restrict__ Wihb, const float* __restrict__ b_ih,
    const ushortT* __restrict__ ghb, const ushortT* __restrict__ memb,
    ushortT* __restrict__ hnb, int M)
{
  __shared__ short Bsh[24576];    // 384 x 64 bf16 (swzA), 48 KB -> 3 blocks/CU
  const int tid = threadIdx.x;
  const int m0 = blockIdx.x * 64;
  const int l = tid & 63, w = tid >> 6;
  const int lr = l & 15, lq = l >> 4;
  const int r0 = (w >> 1) * 16, c0 = (w & 1) * 64;
  f32x4 acc[3][4] = {};

  for (int ks2 = 0; ks2 < 2; ++ks2) {
    if (ks2) __syncthreads();
    #pragma unroll
    for (int i = 0; i < 6; ++i) {           // 3072 chunks / 512 threads
      int c = i * 512 + tid;
      int row = c >> 3, seg = c & 7;
      *reinterpret_cast<short8*>(&Bsh[swzA(row, seg)]) =
          *reinterpret_cast<const short8*>(Wihb + (size_t)row * 128 + ks2 * 64 + seg * 8);
    }
    __syncthreads();
    #pragma unroll
    for (int ks = 0; ks < 2; ++ks) {
      int m = m0 + r0 + lr;
      int kof = ks2 * 64 + ks * 32 + lq * 8;
      short8 a;
      if (m < M) {
        const float4* p = reinterpret_cast<const float4*>(hf + (size_t)m * 128 + kof);
        const float4* t = reinterpret_cast<const float4*>(te + kof);
        float4 x0 = p[0], x1 = p[1], t0 = t[0], t1 = t[1];
        a[0]=(short)f2bf(x0.x+t0.x); a[1]=(short)f2bf(x0.y+t0.y);
        a[2]=(short)f2bf(x0.z+t0.z); a[3]=(short)f2bf(x0.w+t0.w);
        a[4]=(short)f2bf(x1.x+t1.x); a[5]=(short)f2bf(x1.y+t1.y);
        a[6]=(short)f2bf(x1.z+t1.z); a[7]=(short)f2bf(x1.w+t1.w);
      } else {
        #pragma unroll
        for (int j = 0; j < 8; ++j) a[j] = 0;
      }
      #pragma unroll
      for (int s = 0; s < 3; ++s)
        #pragma unroll
        for (int xi = 0; xi < 4; ++xi) {
          short8 b = *reinterpret_cast<const short8*>(
              &Bsh[swzA(s*128 + c0 + xi*16 + lr, ks*4 + lq)]);
          acc[s][xi] = __builtin_amdgcn_mfma_f32_16x16x32_bf16(a, b, acc[s][xi], 0, 0, 0);
        }
    }
  }
  // GRU epilogue
  #pragma unroll
  for (int xi = 0; xi < 4; ++xi) {
    int x = c0 + xi * 16 + lr;
    float br = b_ih[x], bz = b_ih[128 + x], bn = b_ih[256 + x];
    #pragma unroll
    for (int rr = 0; rr < 4; ++rr) {
      int m = m0 + r0 + lq * 4 + rr;
      if (m >= M) continue;
      int node = m >> 3;
      float ghr = bf2f(ghb[(size_t)node * 384 + x]);
      float ghz = bf2f(ghb[(size_t)node * 384 + 128 + x]);
      float ghn = bf2f(ghb[(size_t)node * 384 + 256 + x]);
      float mem = bf2f(memb[(size_t)node * 128 + x]);
      float rv = sigm(acc[0][xi][rr] + br + ghr);
      float zv = sigm(acc[1][xi][rr] + bz + ghz);
      float nv = tanhf(acc[2][xi][rr] + bn + rv * ghn);
      hnb[(size_t)m * 128 + x] = f2bf((1.f - zv) * nv + zv * mem);
    }
  }
}

// ---------------- pooled partial sums (separate, 256 atomics/address) ----------
__global__ __launch_bounds__(256) void k_pool(const ushortT* __restrict__ hnb,
                                              float* __restrict__ prw, int N)
{
  int tid = threadIdx.x;
  float acc[4] = {0.f, 0.f, 0.f, 0.f};
  for (int n = blockIdx.x; n < N; n += gridDim.x) {
    const ushortT* row = hnb + (size_t)n * 1024;
    #pragma unroll
    for (int j = 0; j < 4; ++j) acc[j] += bf2f(row[tid + j * 256]);
  }
  #pragma unroll
  for (int j = 0; j < 4; ++j) atomicAdd(&prw[tid + j * 256], acc[j]);
}

// ---------------- CSR build ----------------
__global__ void k_hist(const int* __restrict__ srcI, int* __restrict__ cnt, int E)
{
  int e = blockIdx.x * 256 + threadIdx.x;
  if (e < E) atomicAdd(&cnt[srcI[e]], 1);
}

__global__ __launch_bounds__(1024) void k_scan(const int* __restrict__ cnt,
    int* __restrict__ ofs, int* __restrict__ cur, int N)
{
  __shared__ int buf[1024];
  __shared__ int carry;
  int tid = threadIdx.x;
  if (tid == 0) carry = 0;
  __syncthreads();
  for (int base = 0; base < N; base += 1024) {
    int i = base + tid;
    int v = (i < N) ? cnt[i] : 0;
    buf[tid] = v;
    __syncthreads();
    for (int off = 1; off < 1024; off <<= 1) {
      int t = (tid >= off) ? buf[tid - off] : 0;
      __syncthreads();
      buf[tid] += t;
      __syncthreads();
    }
    int excl = carry + buf[tid] - v;
    if (i < N) { ofs[i] = excl; cur[i] = excl; }
    __syncthreads();
    if (tid == 0) carry += buf[1023];
    __syncthreads();
  }
  if (tid == 0) ofs[N] = carry;
}

__global__ void k_fill(const int* __restrict__ srcI, int* __restrict__ cur,
                       int* __restrict__ eid, int E)
{
  int e = blockIdx.x * 256 + threadIdx.x;
  if (e >= E) return;
  int p = atomicAdd(&cur[srcI[e]], 1);
  eid[p] = e;
}

// ---------------- GIN aggregation (CSR gather, bf16) ----------------
template<int LMODE>
__global__ __launch_bounds__(256) void k_agg(const ushortT* __restrict__ hb,
    const ushortT* __restrict__ eab, const float* __restrict__ ew,
    const int* __restrict__ dstI, const int* __restrict__ ofs,
    const int* __restrict__ eid, ushortT* __restrict__ aggb, int N)
{
  int half = threadIdx.x >> 7;
  int x = threadIdx.x & 127;
  int n = blockIdx.x * 2 + half;
  if (n >= N) return;
  float acc[8] = {};
  int beg = ofs[n], end = ofs[n + 1];
  for (int i = beg; i < end; ++i) {
    int e = eid[i];
    int d = dstI[e];
    float eav = bf2f(eab[(size_t)e * 128 + x]);
    const float* ewp = ew + (size_t)e * 8;
    if (LMODE == 1) {
      float m = fmaxf(bf2f(hb[(size_t)d * 128 + x]) + eav, 0.f);
      #pragma unroll
      for (int v = 0; v < 8; ++v) acc[v] += m * ewp[v];
    } else {
      const ushortT* hd = hb + (size_t)d * 1024;
      #pragma unroll
      for (int v = 0; v < 8; ++v)
        acc[v] += fmaxf(bf2f(hd[v * 128 + x]) + eav, 0.f) * ewp[v];
    }
  }
  ushortT* ag = aggb + (size_t)n * 1024;
  #pragma unroll
  for (int v = 0; v < 8; ++v) ag[v * 128 + x] = f2bf(acc[v]);
}

// ---------------- edge gate ----------------
__global__ __launch_bounds__(256) void k_ew(const ushortT* __restrict__ eab,
    const ushortT* __restrict__ memb, const int* __restrict__ srcI,
    const float* __restrict__ W_ewg, const float* __restrict__ b_ewg,
    float* __restrict__ ew, int E)
{
  __shared__ float Wsh[2048];
  __shared__ float bsh[8];
  int tid = threadIdx.x;
  for (int i = tid; i < 2048; i += 256) Wsh[i] = W_ewg[i];
  if (tid < 8) bsh[tid] = b_ewg[tid];
  __syncthreads();
  int wv = tid >> 6, lane = tid & 63;
  int e = blockIdx.x * 4 + wv;
  if (e >= E) return;
  int s = srcI[e];
  float c0 = bf2f(eab[(size_t)e * 128 + lane]);
  float c1 = bf2f(eab[(size_t)e * 128 + 64 + lane]);
  float c2 = bf2f(memb[(size_t)s * 128 + lane]);
  float c3 = bf2f(memb[(size_t)s * 128 + 64 + lane]);
  #pragma unroll
  for (int v = 0; v < 8; ++v) {
    float p = c0 * Wsh[v * 256 + lane] + c1 * Wsh[v * 256 + 64 + lane]
            + c2 * Wsh[v * 256 + 128 + lane] + c3 * Wsh[v * 256 + 192 + lane];
    #pragma unroll
    for (int o = 32; o; o >>= 1) p += __shfl_down(p, o);
    if (lane == 0) ew[(size_t)e * 8 + v] = sigm(p + bsh[v]);
  }
}

// ---------------- multi-tensor f32 -> bf16 ----------------
__global__ void k_cvtall(const float* __restrict__ s0, ushortT* __restrict__ d0, int n0,
                         const float* __restrict__ s1, ushortT* __restrict__ d1, int n1,
                         const float* __restrict__ s2, ushortT* __restrict__ d2, int n2,
                         const float* __restrict__ s3, ushortT* __restrict__ d3, int n3)
{
  int i = blockIdx.x * 256 + threadIdx.x;
  if (i < n0) { d0[i] = f2bf(s0[i]); return; }
  i -= n0;
  if (i < n1) { d1[i] = f2bf(s1[i]); return; }
  i -= n1;
  if (i < n2) { d2[i] = f2bf(s2[i]); return; }
  i -= n2;
  if (i < n3) d3[i] = f2bf(s3[i]);
}

// ---------------- fused small mats + te ----------------
__global__ __launch_bounds__(256) void k_prep(
    const float* __restrict__ Wo_l, const float* __restrict__ Wv_l,
    const float* __restrict__ bv_l, const float* __restrict__ bo_l,
    const float* __restrict__ Wq_l, const float* __restrict__ bq_l,
    const float* __restrict__ Wk_l,
    const float* __restrict__ delta_t, const float* __restrict__ W_t,
    const float* __restrict__ b_t,
    float* __restrict__ Wl2f, float* __restrict__ blv,
    ushortT* __restrict__ Wqkgb, float* __restrict__ bqkg, float* __restrict__ te)
{
  int idx = blockIdx.x * 256 + threadIdx.x;    // 65536 total
  if (idx < 32768) {
    int n = idx >> 8, k = idx & 255;
    float a = 0.f;
    for (int j = 0; j < 128; ++j) a += Wo_l[n * 128 + j] * Wv_l[j * 256 + k];
    Wl2f[idx] = a;
  } else {
    int rem = idx - 32768;
    int n = rem >> 7, j = rem & 127;
    float a = 0.f;
    for (int k = 0; k < 128; ++k) a += Wq_l[k * 128 + j] * Wk_l[k * 256 + n];
    Wqkgb[rem] = f2bf(a);
  }
  if (blockIdx.x == 0 && threadIdx.x < 128) {
    int n = threadIdx.x;
    float a = bo_l[n];
    for (int j = 0; j < 128; ++j) a += Wo_l[n * 128 + j] * bv_l[j];
    blv[n] = a;
  }
  if (blockIdx.x == 1) {
    int n = threadIdx.x;
    float a = 0.f;
    for (int k = 0; k < 128; ++k) a += bq_l[k] * Wk_l[k * 256 + n];
    bqkg[n] = a;
  }
  if (blockIdx.x == 2 && threadIdx.x < 128) {
    int t = threadIdx.x;
    te[t] = sinf(delta_t[0] * W_t[t] + b_t[t]);
  }
}

// ---------------- classifier weight fusion ----------------
__global__ __launch_bounds__(256) void k_prep2(
    const float* __restrict__ Wc1, const float* __restrict__ bc1,
    const float* __restrict__ Wl2f, const float* __restrict__ blv,
    ushortT* __restrict__ Wc1p, float* __restrict__ bc1p)
{
  int idx = blockIdx.x * 256 + threadIdx.x;    // 65536 total
  int n = idx >> 9, k = idx & 511;
  float a;
  if (k < 128) a = Wc1[(size_t)n * 384 + k];
  else if (k < 384) {
    int kk = k - 128;
    a = 0.f;
    for (int j = 0; j < 128; ++j) a += Wc1[(size_t)n * 384 + 128 + j] * Wl2f[j * 256 + kk];
  } else a = Wc1[(size_t)n * 384 + 256 + (k - 384)];
  Wc1p[idx] = f2bf(a);
  if (blockIdx.x == 0 && threadIdx.x < 128) {
    int nn = threadIdx.x;
    float b = bc1[nn];
    for (int j = 0; j < 128; ++j) b += Wc1[(size_t)nn * 384 + 128 + j] * blv[j];
    bc1p[nn] = b;
  }
}

// ---------------- Kg / G for global attention ----------------
__global__ __launch_bounds__(256) void k_kgg(const float* __restrict__ prw,
    const float* __restrict__ Wk_g, const float* __restrict__ Wv_g, const float* __restrict__ bv_g,
    const float* __restrict__ Wo_g, float* __restrict__ Kg, float* __restrict__ G, int N)
{
  __shared__ float pl[1024];
  __shared__ float vg[1024];
  int tid = threadIdx.x;
  float invN = 1.f / (float)N;
  for (int i = tid; i < 1024; i += 256) pl[i] = prw[i] * invN;
  __syncthreads();
  for (int o = tid; o < 1024; o += 256) {
    int v = o >> 7, x = o & 127;
    float a = 0.f, b = 0.f;
    for (int k = 0; k < 128; ++k) {
      float p = pl[v * 128 + k];
      a += p * Wk_g[(size_t)x * 128 + k];
      b += p * Wv_g[(size_t)x * 128 + k];
    }
    Kg[o] = a;
    vg[o] = b + bv_g[x];
  }
  __syncthreads();
  for (int o = tid; o < 1024; o += 256) {
    int v = o >> 7, x = o & 127;
    float a = 0.f;
    for (int k = 0; k < 128; ++k) a += vg[v * 128 + k] * Wo_g[(size_t)x * 128 + k];
    G[o] = a;
  }
}

// ---------------- global-score projection rows ----------------
__global__ __launch_bounds__(256) void k_sc(const float* __restrict__ Kg,
    const float* __restrict__ Wq_g, const float* __restrict__ bq_g,
    ushortT* __restrict__ Wqkgb, float* __restrict__ bqkg)
{
  int idx = blockIdx.x * 256 + threadIdx.x;    // 1024
  int v = idx >> 7, j = idx & 127;
  float a = 0.f;
  for (int x = 0; x < 128; ++x) a += Kg[v * 128 + x] * Wq_g[(size_t)x * 128 + j];
  Wqkgb[(size_t)(256 + v) * 128 + j] = f2bf(a);
  if (blockIdx.x == 0 && threadIdx.x < 8) {
    int vv = threadIdx.x;
    float b = 0.f;
    for (int x = 0; x < 128; ++x) b += bq_g[x] * Kg[vv * 128 + x];
    bqkg[256 + vv] = b;
  }
}

// ---------------- fused local+global attention: 2 edges/wave ----------------
__global__ __launch_bounds__(256) void k_lg(
    const ushortT* __restrict__ hnb, const ushortT* __restrict__ qkgb,
    const int* __restrict__ srcI, const int* __restrict__ dstI,
    const float* __restrict__ G, const float* __restrict__ bo_g,
    float* __restrict__ ag_out, ushortT* __restrict__ wsd,
    ushortT* __restrict__ glbb, int E)
{
  __shared__ float Gs[1024], bsh[128];
  int tid = threadIdx.x;
  for (int i = tid; i < 1024; i += 256) Gs[i] = G[i];
  if (tid < 128) bsh[tid] = bo_g[tid];
  __syncthreads();
  int w = tid >> 6, l = tid & 63, half = l >> 5, l31 = l & 31;
  int e = blockIdx.x * 8 + w * 2 + half;
  int ec = (e < E) ? e : (E - 1);
  int s = srcI[ec], d = dstI[ec];
  const uint2* qrow = reinterpret_cast<const uint2*>(qkgb + (size_t)ec * 264);
  uint2 q1u = qrow[l31], q2u = qrow[32 + l31];
  uint4 scu = *reinterpret_cast<const uint4*>(qkgb + (size_t)ec * 264 + 256);
  const uint2* srow = reinterpret_cast<const uint2*>(hnb + (size_t)s * 1024);
  const uint2* drow = reinterpret_cast<const uint2*>(hnb + (size_t)d * 1024);
  uint2 su[8], du[8];
  #pragma unroll
  for (int v = 0; v < 8; ++v) { su[v] = srow[v * 32 + l31]; du[v] = drow[v * 32 + l31]; }
  float q1f[4] = {bflo(q1u.x), bfhi(q1u.x), bflo(q1u.y), bfhi(q1u.y)};
  float q2f[4] = {bflo(q2u.x), bfhi(q2u.x), bflo(q2u.y), bfhi(q2u.y)};
  float pl[8];
  #pragma unroll
  for (int v = 0; v < 8; ++v) {
    pl[v] = q1f[0] * bflo(su[v].x) + q1f[1] * bfhi(su[v].x)
          + q1f[2] * bflo(su[v].y) + q1f[3] * bfhi(su[v].y)
          + q2f[0] * bflo(du[v].x) + q2f[1] * bfhi(du[v].x)
          + q2f[2] * bflo(du[v].y) + q2f[3] * bfhi(du[v].y);
  }
  #pragma unroll
  for (int v = 0; v < 8; ++v) {
    #pragma unroll
    for (int m = 1; m <= 16; m <<= 1) pl[v] += __shfl_xor(pl[v], m);
  }
  const float scale = 0.08838834764831845f;   // 1/sqrt(128)
  float mx = fmaxf(fmaxf(fmaxf(pl[0], pl[1]), fmaxf(pl[2], pl[3])),
                   fmaxf(fmaxf(pl[4], pl[5]), fmaxf(pl[6], pl[7])));
  float suml = 0.f, al[8];
  #pragma unroll
  for (int v = 0; v < 8; ++v) { al[v] = __expf((pl[v] - mx) * scale); suml += al[v]; }
  float invl = 1.f / suml;
  float ws0 = 0.f, ws1 = 0.f, ws2 = 0.f, ws3 = 0.f;
  float wd0 = 0.f, wd1 = 0.f, wd2 = 0.f, wd3 = 0.f;
  #pragma unroll
  for (int v = 0; v < 8; ++v) {
    float a = al[v];
    ws0 += a * bflo(su[v].x); ws1 += a * bfhi(su[v].x);
    ws2 += a * bflo(su[v].y); ws3 += a * bfhi(su[v].y);
    wd0 += a * bflo(du[v].x); wd1 += a * bfhi(du[v].x);
    wd2 += a * bflo(du[v].y); wd3 += a * bfhi(du[v].y);
  }
  if (e < E) {
    uint2* wrow = reinterpret_cast<uint2*>(wsd + (size_t)e * 256);
    uint2 t0; t0.x = pk2bf(ws0 * invl, ws1 * invl); t0.y = pk2bf(ws2 * invl, ws3 * invl);
    uint2 t1; t1.x = pk2bf(wd0 * invl, wd1 * invl); t1.y = pk2bf(wd2 * invl, wd3 * invl);
    wrow[l31] = t0;
    wrow[32 + l31] = t1;
  }
  float sg[8] = {bflo(scu.x), bfhi(scu.x), bflo(scu.y), bfhi(scu.y),
                 bflo(scu.z), bfhi(scu.z), bflo(scu.w), bfhi(scu.w)};
  float mg = fmaxf(fmaxf(fmaxf(sg[0], sg[1]), fmaxf(sg[2], sg[3])),
                   fmaxf(fmaxf(sg[4], sg[5]), fmaxf(sg[6], sg[7])));
  float sumg = 0.f, ag[8];
  #pragma unroll
  for (int v = 0; v < 8; ++v) { ag[v] = __expf((sg[v] - mg) * scale); sumg += ag[v]; }
  float invg = 1.f / sumg;
  if (e < E && l31 < 8) ag_out[(size_t)e * 8 + l31] = ag[l31] * invg;
  float4 b4 = *reinterpret_cast<const float4*>(&bsh[4 * l31]);
  float g0 = b4.x, g1 = b4.y, g2 = b4.z, g3 = b4.w;
  #pragma unroll
  for (int v = 0; v < 8; ++v) {
    float sv = ag[v] * invg;
    float4 gv = *reinterpret_cast<const float4*>(&Gs[v * 128 + 4 * l31]);
    g0 += sv * gv.x; g1 += sv * gv.y; g2 += sv * gv.z; g3 += sv * gv.w;
  }
  if (e < E) {
    uint2 t; t.x = pk2bf(g0, g1); t.y = pk2bf(g2, g3);
    reinterpret_cast<uint2*>(glbb + (size_t)e * 128)[l31] = t;
  }
}

// ---------------- logits ----------------
__global__ __launch_bounds__(256) void k_logits(const ushortT* __restrict__ hid,
    const float* __restrict__ Wc2, const float* __restrict__ bc2,
    float* __restrict__ logits, int E)
{
  __shared__ float Wsh[640];
  __shared__ float bsh[5];
  int tid = threadIdx.x;
  for (int i = tid; i < 640; i += 256) Wsh[i] = Wc2[i];
  if (tid < 5) bsh[tid] = bc2[tid];
  __syncthreads();
  int wv = tid >> 6, lane = tid & 63;
  int e = blockIdx.x * 4 + wv;
  if (e >= E) return;
  float h0 = bf2f(hid[(size_t)e * 128 + lane]), h1 = bf2f(hid[(size_t)e * 128 + 64 + lane]);
  #pragma unroll
  for (int c = 0; c < 5; ++c) {
    float p = h0 * Wsh[c * 128 + lane] + h1 * Wsh[c * 128 + 64 + lane];
    #pragma unroll
    for (int o = 32; o; o >>= 1) p += __shfl_down(p, o);
    if (lane == 0) logits[(size_t)e * 5 + c] = p + bsh[c];
  }
}

extern "C" void kernel_launch(void* const* d_in, const int* in_sizes, int n_in,
                              void* d_out, int out_size, void* d_ws, size_t ws_size,
                              hipStream_t stream)
{
  const int*   edge_index = (const int*)d_in[0];
  const float* edge_attr  = (const float*)d_in[1];
  const float* delta_t    = (const float*)d_in[2];
  const float* memory     = (const float*)d_in[3];
  const float* W_ee  = (const float*)d_in[4];
  const float* b_ee  = (const float*)d_in[5];
  const float* W_ewg = (const float*)d_in[6];
  const float* b_ewg = (const float*)d_in[7];
  const float* gin_W1 = (const float*)d_in[8];
  const float* gin_b1 = (const float*)d_in[9];
  const float* gin_W2 = (const float*)d_in[10];
  const float* gin_b2 = (const float*)d_in[11];
  const float* W_t  = (const float*)d_in[12];
  const float* b_t  = (const float*)d_in[13];
  const float* W_ih = (const float*)d_in[14];
  const float* b_ih = (const float*)d_in[15];
  const float* W_hh = (const float*)d_in[16];
  const float* b_hh = (const float*)d_in[17];
  const float* Wq_l = (const float*)d_in[20];
  const float* bq_l = (const float*)d_in[21];
  const float* Wk_l = (const float*)d_in[22];
  const float* Wv_l = (const float*)d_in[24];
  const float* bv_l = (const float*)d_in[25];
  const float* Wo_l = (const float*)d_in[26];
  const float* bo_l = (const float*)d_in[27];
  const float* Wq_g = (const float*)d_in[28];
  const float* bq_g = (const float*)d_in[29];
  const float* Wk_g = (const float*)d_in[30];
  const float* Wv_g = (const float*)d_in[32];
  const float* bv_g = (const float*)d_in[33];
  const float* Wo_g = (const float*)d_in[34];
  const float* bo_g = (const float*)d_in[35];
  const float* Wc1  = (const float*)d_in[36];
  const float* bc1  = (const float*)d_in[37];
  const float* Wc2  = (const float*)d_in[38];
  const float* bc2  = (const float*)d_in[39];

  const int E = in_sizes[0] / 2;
  const int N = in_sizes[3] / HSZ;
  const int* srcI = edge_index;
  const int* dstI = edge_index + E;

  float* out    = (float*)d_out;
  float* logits = out;
  float* ew     = out + (size_t)E * 5;
  float* h      = out + (size_t)E * 13;                       // h_before (N,8,128) f32
  float* ag_out = out + (size_t)E * 13 + (size_t)N * 1024;

  // ---- workspace arena (units: f32 slots) ----
  float* ws = (float*)d_ws;
  size_t off = 0;
  auto alloc = [&](size_t n) { size_t o = off; off += (n + 255) & ~(size_t)255; return o; };
  float* te   = ws + alloc(128);
  float* blv  = ws + alloc(128);
  float* bqkg = ws + alloc(384);
  float* bc1p = ws + alloc(128);
  float* Kg   = ws + alloc(1024);
  float* G    = ws + alloc(1024);
  float* prw  = ws + alloc(1024);
  int* cnt = (int*)(ws + alloc(N));
  int* ofs = (int*)(ws + alloc(N + 1));
  int* cur = (int*)(ws + alloc(N));
  int* eid = (int*)(ws + alloc(E));
  ushortT* memb   = (ushortT*)(ws + alloc((size_t)N * 64));
  ushortT* eab    = (ushortT*)(ws + alloc((size_t)E * 64));
  ushortT* h1b    = (ushortT*)(ws + alloc((size_t)N * 512));
  ushortT* hnb    = (ushortT*)(ws + alloc((size_t)N * 512));
  ushortT* ghb    = (ushortT*)(ws + alloc((size_t)N * 192));
  ushortT* ginW1b = (ushortT*)(ws + alloc(16384));
  ushortT* ginW2b = (ushortT*)(ws + alloc(16384));
  ushortT* Wihb   = (ushortT*)(ws + alloc(24576));
  float*   Wl2f   = ws + alloc(32768);
  ushortT* Wc1p   = (ushortT*)(ws + alloc(32768));   // 128 x 512 bf16
  ushortT* Wqkgb  = (ushortT*)(ws + alloc(16896));   // 264 x 128 bf16
  // BR union: aggb (N*512) | attn {qkgb 132E | wsd 128E | glbb 64E} (324E)
  size_t brA = (size_t)N * 512, brC = (size_t)E * 324;
  size_t brsz = brA > brC ? brA : brC;
  float* BR = ws + alloc(brsz);
  if (ws_size < off * sizeof(float)) return;   // needs ~130 MiB

  ushortT* aggb = (ushortT*)BR;
  ushortT* qkgb = (ushortT*)BR;                        // E x 264
  ushortT* wsd  = (ushortT*)(BR + (size_t)E * 132);    // E x 256
  ushortT* glbb = (ushortT*)(BR + (size_t)E * 260);    // E x 128
  ushortT* hid  = (ushortT*)BR;                        // E x 128 (over dead qkgb)

  auto cdiv = [](int a, int b) { return (a + b - 1) / b; };

  // 0. CSR + bf16 mirrors/weights + zero pool accumulator
  hipMemsetAsync(cnt, 0, (size_t)N * sizeof(int), stream);
  hipMemsetAsync(prw, 0, 1024 * sizeof(float), stream);
  k_hist<<<cdiv(E, 256), 256, 0, stream>>>(srcI, cnt, E);
  k_scan<<<1, 1024, 0, stream>>>(cnt, ofs, cur, N);
  k_fill<<<cdiv(E, 256), 256, 0, stream>>>(srcI, cur, eid, E);
  {
    int total = N * 128 + 32768 + 32768 + 49152;
    k_cvtall<<<cdiv(total, 256), 256, 0, stream>>>(
        memory, memb, N * 128, gin_W1, ginW1b, 32768,
        gin_W2, ginW2b, 32768, W_ih, Wihb, 49152);
  }
  // 1. ea = relu(edge_attr @ W_ee^T + b_ee) -> bf16
  gemm_bf<0, 1, true, false, false><<<dim3(cdiv(E, 128), 1), 256, 0, stream>>>(
      edge_attr, nullptr, nullptr, W_ee, b_ee, eab, E, 59, 128);
  // 2. ew + prep(+te) + prep2 + gh
  k_ew<<<cdiv(E, 4), 256, 0, stream>>>(eab, memb, srcI, W_ewg, b_ewg, ew, E);
  k_prep<<<256, 256, 0, stream>>>(Wo_l, Wv_l, bv_l, bo_l, Wq_l, bq_l, Wk_l,
                                  delta_t, W_t, b_t, Wl2f, blv, Wqkgb, bqkg, te);
  k_prep2<<<256, 256, 0, stream>>>(Wc1, bc1, Wl2f, blv, Wc1p, bc1p);
  gemm_bf<0, 0, true, false, false><<<dim3(cdiv(N, 128), 3), 256, 0, stream>>>(
      memory, nullptr, nullptr, W_hh, b_hh, ghb, N, 128, 384);
  // 3. GIN layer 1 (h == broadcast memory)
  k_agg<1><<<cdiv(N, 2), 256, 0, stream>>>(memb, eab, ew, dstI, ofs, eid, aggb, N);
  k_gin<1><<<cdiv(N * 8, 128), 256, 0, stream>>>(
      memb, aggb, nullptr, h1b, ginW1b, gin_b1, ginW2b, gin_b2, N * 8);
  // 4. GIN layer 2 -> h (d_out f32)
  k_agg<2><<<cdiv(N, 2), 256, 0, stream>>>(h1b, eab, ew, dstI, ofs, eid, aggb, N);
  k_gin<2><<<cdiv(N * 8, 128), 256, 0, stream>>>(
      h1b, aggb, h, nullptr, ginW1b + 16384, gin_b1 + 128,
      ginW2b + 16384, gin_b2 + 128, N * 8);
  // 5. fused gi GEMM + GRU -> hnb; pooled partials separately
  k_giru<<<cdiv(N * 8, 64), 512, 0, stream>>>(h, te, Wihb, b_ih, ghb, memb, hnb, N * 8);
  k_pool<<<256, 256, 0, stream>>>(hnb, prw, N);
  // 6. global K/G + score-projection rows
  k_kgg<<<1, 256, 0, stream>>>(prw, Wk_g, Wv_g, bv_g, Wo_g, Kg, G, N);
  k_sc<<<4, 256, 0, stream>>>(Kg, Wq_g, bq_g, Wqkgb, bqkg);
  // 7. fused q projections + global scores (Nout=264)
  gemm_bf<0, 0, true, true, true><<<dim3(cdiv(E, 128), 3), 256, 0, stream>>>(
      eab, nullptr, nullptr, Wqkgb, bqkg, qkgb, E, 128, 264);
  // 8. fused local+global attention (2 edges/wave)
  k_lg<<<cdiv(E, 8), 256, 0, stream>>>(hnb, qkgb, srcI, dstI, G, bo_g,
                                       ag_out, wsd, glbb, E);
  // 9. classifier (localout folded in): K=512 over {ea, wsd, glbb}
  gemm_bf<4, 1, true, true, true><<<dim3(cdiv(E, 128), 1), 256, 0, stream>>>(
      eab, wsd, glbb, Wc1p, bc1p, hid, E, 512, 128);
  k_logits<<<cdiv(E, 4), 256, 0, stream>>>(hid, Wc2, bc2, logits, E);
}